// Round 1
// baseline (1105.208 us; speedup 1.0000x reference)
//
#include <hip/hip_runtime.h>
#include <math.h>

#define N_NODES 8192
#define NFEAT 512
#define NHID 512
#define NCLASS 8
#define RCAP 192   // max row degree; Binomial(8192,0.01): mean 82, std 9 -> 192 is ~12 sigma

// ---------------- adjacency: dense 0/1 -> ELL (single 256MB pass) ----------------
__global__ __launch_bounds__(256) void build_ell(const float* __restrict__ adj,
                                                 int* __restrict__ colidx,
                                                 int* __restrict__ deg) {
  int row = blockIdx.x;
  __shared__ int cnt;
  __shared__ int cols[RCAP];
  if (threadIdx.x == 0) cnt = 0;
  __syncthreads();
  const float4* arow = (const float4*)(adj + (size_t)row * N_NODES);
  for (int i = threadIdx.x; i < N_NODES / 4; i += 256) {
    float4 v = arow[i];
    int base = i * 4;
    if (v.x > 0.5f) { int p = atomicAdd(&cnt, 1); if (p < RCAP) cols[p] = base; }
    if (v.y > 0.5f) { int p = atomicAdd(&cnt, 1); if (p < RCAP) cols[p] = base + 1; }
    if (v.z > 0.5f) { int p = atomicAdd(&cnt, 1); if (p < RCAP) cols[p] = base + 2; }
    if (v.w > 0.5f) { int p = atomicAdd(&cnt, 1); if (p < RCAP) cols[p] = base + 3; }
  }
  __syncthreads();
  int d = cnt < RCAP ? cnt : RCAP;
  if (threadIdx.x == 0) deg[row] = d;
  for (int i = threadIdx.x; i < d; i += 256) colidx[(size_t)row * RCAP + i] = cols[i];
}

// ---------------- 512x512 transpose ----------------
__global__ void transpose512(const float* __restrict__ in, float* __restrict__ out) {
  __shared__ float tile[32][33];
  int x = blockIdx.x * 32 + threadIdx.x;
  int y0 = blockIdx.y * 32;
  for (int i = threadIdx.y; i < 32; i += 8)
    tile[i][threadIdx.x] = in[(size_t)(y0 + i) * 512 + x];
  __syncthreads();
  int xo = blockIdx.y * 32 + threadIdx.x;
  int yo0 = blockIdx.x * 32;
  for (int i = threadIdx.y; i < 32; i += 8)
    out[(size_t)(yo0 + i) * 512 + xo] = tile[threadIdx.x][i];
}

// ---------------- fp32 tiled SGEMM: C = A[MxK] @ B[KxN] (+bias per column) ----------------
// 64x64 tile, BK=16, 256 threads, 4x4 micro-tile. Requires M%64==0, N%64==0, K%16==0.
__global__ __launch_bounds__(256) void sgemm_nn(const float* __restrict__ A,
                                                const float* __restrict__ B,
                                                const float* __restrict__ bias,
                                                float* __restrict__ C,
                                                int M, int Nn, int K) {
  __shared__ float As[16][68];  // padded: conflict-free transposed stores, 16B-aligned rows
  __shared__ float Bs[16][64];
  const int tid = threadIdx.x;
  const int bm = blockIdx.y * 64, bn = blockIdx.x * 64;
  const int tx = tid & 15, ty = tid >> 4;
  const int arow = tid >> 2, acol = (tid & 3) << 2;
  const int brow = tid >> 4, bcol = (tid & 15) << 2;
  float acc[4][4];
#pragma unroll
  for (int i = 0; i < 4; ++i)
#pragma unroll
    for (int j = 0; j < 4; ++j) acc[i][j] = 0.f;

  const float* Aptr = A + (size_t)(bm + arow) * K + acol;
  const float* Bptr = B + (size_t)brow * Nn + bn + bcol;

  for (int k0 = 0; k0 < K; k0 += 16) {
    float4 av = *(const float4*)(Aptr + k0);
    float4 bv = *(const float4*)(Bptr + (size_t)k0 * Nn);
    As[acol + 0][arow] = av.x;
    As[acol + 1][arow] = av.y;
    As[acol + 2][arow] = av.z;
    As[acol + 3][arow] = av.w;
    *(float4*)&Bs[brow][bcol] = bv;
    __syncthreads();
#pragma unroll
    for (int kk = 0; kk < 16; ++kk) {
      float4 a4 = *(const float4*)&As[kk][ty << 2];
      float4 b4 = *(const float4*)&Bs[kk][tx << 2];
      float ar[4] = {a4.x, a4.y, a4.z, a4.w};
      float br[4] = {b4.x, b4.y, b4.z, b4.w};
#pragma unroll
      for (int i = 0; i < 4; ++i)
#pragma unroll
        for (int j = 0; j < 4; ++j) acc[i][j] = fmaf(ar[i], br[j], acc[i][j]);
    }
    __syncthreads();
  }
#pragma unroll
  for (int i = 0; i < 4; ++i) {
    float4 o = make_float4(acc[i][0], acc[i][1], acc[i][2], acc[i][3]);
    if (bias) {
      o.x += bias[bn + (tx << 2) + 0];
      o.y += bias[bn + (tx << 2) + 1];
      o.z += bias[bn + (tx << 2) + 2];
      o.w += bias[bn + (tx << 2) + 3];
    }
    *(float4*)(C + (size_t)(bm + (ty << 2) + i) * Nn + bn + (tx << 2)) = o;
  }
}

// ---------------- rank-1 bias helpers: u = Qw@Kb, w = Kw@Qb, c = Qb.Kb ----------------
__global__ __launch_bounds__(64) void bias_prep(const float* __restrict__ Qw, const float* __restrict__ Kw,
                                                const float* __restrict__ Qb, const float* __restrict__ Kb,
                                                float* __restrict__ u, float* __restrict__ w,
                                                float* __restrict__ cbuf) {
  int k = blockIdx.x;
  int lane = threadIdx.x;
  if (k == NHID) {
    float s = 0.f;
    for (int j = lane; j < NHID; j += 64) s = fmaf(Qb[j], Kb[j], s);
#pragma unroll
    for (int o = 32; o > 0; o >>= 1) s += __shfl_down(s, o, 64);
    if (lane == 0) cbuf[0] = s;
    return;
  }
  float su = 0.f, sw = 0.f;
  for (int j = lane; j < NHID; j += 64) {
    su = fmaf(Qw[(size_t)k * NHID + j], Kb[j], su);
    sw = fmaf(Kw[(size_t)k * NHID + j], Qb[j], sw);
  }
#pragma unroll
  for (int o = 32; o > 0; o >>= 1) { su += __shfl_down(su, o, 64); sw += __shfl_down(sw, o, 64); }
  if (lane == 0) { u[k] = su; w[k] = sw; }
}

// ---------------- h = relu(adj @ xW + b1)  (row-gather SpMM) ----------------
__global__ __launch_bounds__(256) void spmm_bias_relu(const float* __restrict__ xW,
                                                      const int* __restrict__ colidx,
                                                      const int* __restrict__ deg,
                                                      const float* __restrict__ bias,
                                                      float* __restrict__ h) {
  int row = blockIdx.x;
  int d = deg[row];
  __shared__ int scols[RCAP];
  int t = threadIdx.x;
  for (int i = t; i < d; i += 256) scols[i] = colidx[(size_t)row * RCAP + i];
  __syncthreads();
  float2 acc = make_float2(0.f, 0.f);
  for (int e = 0; e < d; ++e) {
    float2 v = ((const float2*)(xW + (size_t)scols[e] * NHID))[t];
    acc.x += v.x;
    acc.y += v.y;
  }
  float2 bv = ((const float2*)bias)[t];
  float2 o = make_float2(fmaxf(acc.x + bv.x, 0.f), fmaxf(acc.y + bv.y, 0.f));
  ((float2*)(h + (size_t)row * NHID))[t] = o;
}

// ---------------- a_i = h_i.u, b_i = h_i.w (one wave per row) ----------------
__global__ __launch_bounds__(256) void dual_matvec(const float* __restrict__ h, const float* __restrict__ u,
                                                   const float* __restrict__ w, float* __restrict__ a_vec,
                                                   float* __restrict__ b_vec) {
  int t = threadIdx.x;
  int wv = t >> 6, lane = t & 63;
  int row = blockIdx.x * 4 + wv;
  const float2* hr = (const float2*)(h + (size_t)row * NHID);
  const float2* ur = (const float2*)u;
  const float2* wr = (const float2*)w;
  float sa = 0.f, sb = 0.f;
  for (int i = lane; i < NHID / 2; i += 64) {
    float2 hv = hr[i], uv = ur[i], wv2 = wr[i];
    sa = fmaf(hv.x, uv.x, sa); sa = fmaf(hv.y, uv.y, sa);
    sb = fmaf(hv.x, wv2.x, sb); sb = fmaf(hv.y, wv2.y, sb);
  }
#pragma unroll
  for (int o = 32; o > 0; o >>= 1) { sa += __shfl_down(sa, o, 64); sb += __shfl_down(sb, o, 64); }
  if (lane == 0) { a_vec[row] = sa; b_vec[row] = sb; }
}

// ---------------- edge scores s_ij = G_i.h_j + a_i + b_j + c, then full-row softmax ----------------
// Masked (zero) entries contribute (N-d)*exp(-m) to the denominator; background weight c_i stored.
__global__ __launch_bounds__(256) void edge_softmax(const float* __restrict__ G, const float* __restrict__ h,
                                                    const int* __restrict__ colidx, const int* __restrict__ deg,
                                                    const float* __restrict__ a_vec, const float* __restrict__ b_vec,
                                                    const float* __restrict__ cbuf,
                                                    float* __restrict__ edge_w, float* __restrict__ row_c) {
  int row = blockIdx.x;
  int d = deg[row];
  __shared__ float gs[NHID];
  __shared__ int scols[RCAP];
  __shared__ float sv[RCAP];
  __shared__ float red[256];
  int t = threadIdx.x;
  ((float2*)gs)[t] = ((const float2*)(G + (size_t)row * NHID))[t];
  for (int i = t; i < d; i += 256) scols[i] = colidx[(size_t)row * RCAP + i];
  __syncthreads();
  int wv = t >> 6, lane = t & 63;
  float ai = a_vec[row] + cbuf[0];
  for (int e = wv; e < d; e += 4) {
    int col = scols[e];
    const float2* hr = (const float2*)(h + (size_t)col * NHID);
    const float2* gr = (const float2*)gs;
    float s = 0.f;
    for (int i = lane; i < NHID / 2; i += 64) {
      float2 hv = hr[i], gv = gr[i];
      s = fmaf(hv.x, gv.x, s);
      s = fmaf(hv.y, gv.y, s);
    }
#pragma unroll
    for (int o = 32; o > 0; o >>= 1) s += __shfl_down(s, o, 64);
    if (lane == 0) sv[e] = s + ai + b_vec[col];
  }
  __syncthreads();
  // row max over edge scores AND the implicit zeros (background)
  float m = 0.f;
  for (int i = t; i < d; i += 256) m = fmaxf(m, sv[i]);
  red[t] = m;
  __syncthreads();
  for (int s2 = 128; s2 > 0; s2 >>= 1) { if (t < s2) red[t] = fmaxf(red[t], red[t + s2]); __syncthreads(); }
  m = red[0];
  __syncthreads();
  float ssum = 0.f;
  for (int i = t; i < d; i += 256) { float ex = expf(sv[i] - m); sv[i] = ex; ssum += ex; }
  red[t] = ssum;
  __syncthreads();
  for (int s2 = 128; s2 > 0; s2 >>= 1) { if (t < s2) red[t] += red[t + s2]; __syncthreads(); }
  float denom = red[0] + (float)(N_NODES - d) * expf(-m);
  float inv = 1.f / denom;
  for (int i = t; i < d; i += 256) edge_w[(size_t)row * RCAP + i] = sv[i] * inv;
  if (t == 0) row_c[row] = expf(-m) * inv;
}

// ---------------- T = colsum(Vh) ----------------
__global__ void zero_vec(float* __restrict__ T) { T[threadIdx.x] = 0.f; }

__global__ __launch_bounds__(256) void colsum_atomic(const float* __restrict__ Vh, float* __restrict__ T) {
  int t = threadIdx.x;
  int r0 = blockIdx.x * 128;
  float2 s = make_float2(0.f, 0.f);
  for (int r = 0; r < 128; ++r) {
    float2 v = ((const float2*)(Vh + (size_t)(r0 + r) * NHID))[t];
    s.x += v.x;
    s.y += v.y;
  }
  atomicAdd(&T[2 * t], s.x);
  atomicAdd(&T[2 * t + 1], s.y);
}

// ---------------- X_tilde = sum_edges (w-c)*Vh[col] + c*T, then LayerNorm ----------------
__global__ __launch_bounds__(256) void aggregate_ln(const float* __restrict__ Vh, const int* __restrict__ colidx,
                                                    const int* __restrict__ deg, const float* __restrict__ edge_w,
                                                    const float* __restrict__ row_c, const float* __restrict__ T,
                                                    const float* __restrict__ g, const float* __restrict__ b,
                                                    float* __restrict__ Xt) {
  int row = blockIdx.x;
  int d = deg[row];
  float ci = row_c[row];
  __shared__ int scols[RCAP];
  __shared__ float sw[RCAP];
  __shared__ float red1[256], red2[256];
  int t = threadIdx.x;
  for (int i = t; i < d; i += 256) {
    scols[i] = colidx[(size_t)row * RCAP + i];
    sw[i] = edge_w[(size_t)row * RCAP + i] - ci;
  }
  __syncthreads();
  float2 acc = make_float2(0.f, 0.f);
  for (int e = 0; e < d; ++e) {
    float wgt = sw[e];
    float2 v = ((const float2*)(Vh + (size_t)scols[e] * NHID))[t];
    acc.x = fmaf(wgt, v.x, acc.x);
    acc.y = fmaf(wgt, v.y, acc.y);
  }
  float2 tv = ((const float2*)T)[t];
  acc.x = fmaf(ci, tv.x, acc.x);
  acc.y = fmaf(ci, tv.y, acc.y);
  red1[t] = acc.x + acc.y;
  red2[t] = acc.x * acc.x + acc.y * acc.y;
  __syncthreads();
  for (int s2 = 128; s2 > 0; s2 >>= 1) {
    if (t < s2) { red1[t] += red1[t + s2]; red2[t] += red2[t + s2]; }
    __syncthreads();
  }
  float mu = red1[0] * (1.f / NHID);
  float var = red2[0] * (1.f / NHID) - mu * mu;
  float rstd = rsqrtf(var + 1e-5f);
  float2 gv = ((const float2*)g)[t];
  float2 bv = ((const float2*)b)[t];
  float2 o;
  o.x = (acc.x - mu) * rstd * gv.x + bv.x;
  o.y = (acc.y - mu) * rstd * gv.y + bv.y;
  ((float2*)(Xt + (size_t)row * NHID))[t] = o;
}

// ---------------- Y = Xt @ W2 (512 -> 8), one wave per row ----------------
__global__ __launch_bounds__(256) void xt_w2(const float* __restrict__ Xt, const float* __restrict__ W2,
                                             float* __restrict__ Y) {
  __shared__ float w2s[NHID * NCLASS];
  int t = threadIdx.x;
  for (int i = t; i < NHID * NCLASS; i += 256) w2s[i] = W2[i];
  __syncthreads();
  int wv = t >> 6, lane = t & 63;
  int row = blockIdx.x * 4 + wv;
  const float4* xr = (const float4*)(Xt + (size_t)row * NHID);
  float4 x0 = xr[lane * 2], x1 = xr[lane * 2 + 1];
  float xv[8] = {x0.x, x0.y, x0.z, x0.w, x1.x, x1.y, x1.z, x1.w};
  float acc[NCLASS];
#pragma unroll
  for (int c = 0; c < NCLASS; ++c) acc[c] = 0.f;
#pragma unroll
  for (int kk = 0; kk < 8; ++kk) {
    int k = lane * 8 + kk;
#pragma unroll
    for (int c = 0; c < NCLASS; ++c) acc[c] = fmaf(xv[kk], w2s[k * NCLASS + c], acc[c]);
  }
#pragma unroll
  for (int c = 0; c < NCLASS; ++c)
#pragma unroll
    for (int o = 32; o > 0; o >>= 1) acc[c] += __shfl_down(acc[c], o, 64);
  if (lane == 0) {
    *(float4*)(Y + (size_t)row * NCLASS) = make_float4(acc[0], acc[1], acc[2], acc[3]);
    *(float4*)(Y + (size_t)row * NCLASS + 4) = make_float4(acc[4], acc[5], acc[6], acc[7]);
  }
}

// ---------------- z = adj @ Y + b2, softmax over 8 classes ----------------
__global__ __launch_bounds__(256) void final_spmm_softmax(const float* __restrict__ Y,
                                                          const int* __restrict__ colidx,
                                                          const int* __restrict__ deg,
                                                          const float* __restrict__ b2,
                                                          float* __restrict__ out) {
  int t = threadIdx.x;
  int wv = t >> 6, lane = t & 63;
  int row = blockIdx.x * 4 + wv;
  int d = deg[row];
  const int* cols = colidx + (size_t)row * RCAP;
  float acc[8];
#pragma unroll
  for (int c = 0; c < 8; ++c) acc[c] = 0.f;
  for (int e = lane; e < d; e += 64) {
    int col = cols[e];
    const float4* yr = (const float4*)(Y + (size_t)col * 8);
    float4 y0 = yr[0], y1 = yr[1];
    acc[0] += y0.x; acc[1] += y0.y; acc[2] += y0.z; acc[3] += y0.w;
    acc[4] += y1.x; acc[5] += y1.y; acc[6] += y1.z; acc[7] += y1.w;
  }
#pragma unroll
  for (int c = 0; c < 8; ++c)
#pragma unroll
    for (int o = 32; o > 0; o >>= 1) acc[c] += __shfl_down(acc[c], o, 64);
  if (lane == 0) {
    float z[8];
    float m = -1e30f;
#pragma unroll
    for (int c = 0; c < 8; ++c) { z[c] = acc[c] + b2[c]; m = fmaxf(m, z[c]); }
    float s = 0.f;
#pragma unroll
    for (int c = 0; c < 8; ++c) { z[c] = expf(z[c] - m); s += z[c]; }
    float inv = 1.f / s;
    *(float4*)(out + (size_t)row * 8) = make_float4(z[0] * inv, z[1] * inv, z[2] * inv, z[3] * inv);
    *(float4*)(out + (size_t)row * 8 + 4) = make_float4(z[4] * inv, z[5] * inv, z[6] * inv, z[7] * inv);
  }
}

extern "C" void kernel_launch(void* const* d_in, const int* in_sizes, int n_in,
                              void* d_out, int out_size, void* d_ws, size_t ws_size,
                              hipStream_t stream) {
  const float* adj = (const float*)d_in[0];
  const float* x = (const float*)d_in[1];
  const float* W1 = (const float*)d_in[2];
  const float* b1 = (const float*)d_in[3];
  const float* Qw = (const float*)d_in[4];
  const float* Qb = (const float*)d_in[5];
  const float* Kw = (const float*)d_in[6];
  const float* Kb = (const float*)d_in[7];
  const float* Vw = (const float*)d_in[8];
  const float* Vb = (const float*)d_in[9];
  const float* ln_g = (const float*)d_in[10];
  const float* ln_b = (const float*)d_in[11];
  const float* W2 = (const float*)d_in[12];
  const float* b2 = (const float*)d_in[13];
  float* out = (float*)d_out;

  char* ws = (char*)d_ws;
  size_t off = 0;
  auto alloc = [&](size_t bytes) -> void* {
    void* p = ws + off;
    off = (off + bytes + 255) & ~(size_t)255;
    return p;
  };
  int* colidx = (int*)alloc((size_t)N_NODES * RCAP * 4);
  int* deg = (int*)alloc((size_t)N_NODES * 4);
  float* bufA = (float*)alloc((size_t)N_NODES * NHID * 4);  // xW, then G = h@M
  float* bufB = (float*)alloc((size_t)N_NODES * NHID * 4);  // h, then X_tilde
  float* Vh = (float*)alloc((size_t)N_NODES * NHID * 4);
  float* KwT = (float*)alloc((size_t)512 * 512 * 4);
  float* Mmat = (float*)alloc((size_t)512 * 512 * 4);
  float* edge_w = (float*)alloc((size_t)N_NODES * RCAP * 4);
  float* row_c = (float*)alloc((size_t)N_NODES * 4);
  float* a_vec = (float*)alloc((size_t)N_NODES * 4);
  float* b_vec = (float*)alloc((size_t)N_NODES * 4);
  float* u_vec = (float*)alloc((size_t)NHID * 4);
  float* w_vec = (float*)alloc((size_t)NHID * 4);
  float* cbuf = (float*)alloc(256);
  float* T = (float*)alloc((size_t)NHID * 4);
  float* Y = (float*)alloc((size_t)N_NODES * NCLASS * 4);
  (void)in_sizes; (void)n_in; (void)out_size; (void)ws_size;

  // 1) sparse structure from dense adj (256 MB, single pass)
  build_ell<<<N_NODES, 256, 0, stream>>>(adj, colidx, deg);
  // 2) KwT, M = Qw @ Kw^T ; rank-1 bias terms
  transpose512<<<dim3(16, 16), dim3(32, 8), 0, stream>>>(Kw, KwT);
  bias_prep<<<NHID + 1, 64, 0, stream>>>(Qw, Kw, Qb, Kb, u_vec, w_vec, cbuf);
  sgemm_nn<<<dim3(8, 8), 256, 0, stream>>>(Qw, KwT, nullptr, Mmat, 512, 512, 512);
  // 3) xW = x @ W1 ; h = relu(adj @ xW + b1)
  sgemm_nn<<<dim3(8, 128), 256, 0, stream>>>(x, W1, nullptr, bufA, N_NODES, NHID, NFEAT);
  spmm_bias_relu<<<N_NODES, 256, 0, stream>>>(bufA, colidx, deg, b1, bufB);
  // 4) G = h @ M (replaces Qh and Kh GEMMs) ; Vh = h @ Vw + Vb ; a,b vectors
  sgemm_nn<<<dim3(8, 128), 256, 0, stream>>>(bufB, Mmat, nullptr, bufA, N_NODES, NHID, NHID);
  sgemm_nn<<<dim3(8, 128), 256, 0, stream>>>(bufB, Vw, Vb, Vh, N_NODES, NHID, NHID);
  dual_matvec<<<N_NODES / 4, 256, 0, stream>>>(bufB, u_vec, w_vec, a_vec, b_vec);
  // 5) masked scores + full-row softmax (closed-form background)
  edge_softmax<<<N_NODES, 256, 0, stream>>>(bufA, bufB, colidx, deg, a_vec, b_vec, cbuf, edge_w, row_c);
  // 6) T = colsum(Vh); X_tilde (+ LayerNorm) -> bufB
  zero_vec<<<1, 512, 0, stream>>>(T);
  colsum_atomic<<<64, 256, 0, stream>>>(Vh, T);
  aggregate_ln<<<N_NODES, 256, 0, stream>>>(Vh, colidx, deg, edge_w, row_c, T, ln_g, ln_b, bufB);
  // 7) Y = X_tilde @ W2 ; z = adj @ Y + b2 ; softmax
  xt_w2<<<N_NODES / 4, 256, 0, stream>>>(bufB, W2, Y);
  final_spmm_softmax<<<N_NODES / 4, 256, 0, stream>>>(Y, colidx, deg, b2, out);
}

// Round 2
// 1036.503 us; speedup vs baseline: 1.0663x; 1.0663x over previous
//
#include <hip/hip_runtime.h>
#include <math.h>

#define N_NODES 8192
#define NFEAT 512
#define NHID 512
#define NCLASS 8
#define RCAP 192   // max row degree; Binomial(8192,0.01): mean 82, std 9 -> 192 is ~12 sigma

// ---------------- adjacency: dense 0/1 -> ELL (single 256MB pass) ----------------
__global__ __launch_bounds__(256) void build_ell(const float* __restrict__ adj,
                                                 int* __restrict__ colidx,
                                                 int* __restrict__ deg) {
  int row = blockIdx.x;
  __shared__ int cnt;
  __shared__ int cols[RCAP];
  if (threadIdx.x == 0) cnt = 0;
  __syncthreads();
  const float4* arow = (const float4*)(adj + (size_t)row * N_NODES);
  for (int i = threadIdx.x; i < N_NODES / 4; i += 256) {
    float4 v = arow[i];
    int base = i * 4;
    if (v.x > 0.5f) { int p = atomicAdd(&cnt, 1); if (p < RCAP) cols[p] = base; }
    if (v.y > 0.5f) { int p = atomicAdd(&cnt, 1); if (p < RCAP) cols[p] = base + 1; }
    if (v.z > 0.5f) { int p = atomicAdd(&cnt, 1); if (p < RCAP) cols[p] = base + 2; }
    if (v.w > 0.5f) { int p = atomicAdd(&cnt, 1); if (p < RCAP) cols[p] = base + 3; }
  }
  __syncthreads();
  int d = cnt < RCAP ? cnt : RCAP;
  if (threadIdx.x == 0) deg[row] = d;
  for (int i = threadIdx.x; i < d; i += 256) colidx[(size_t)row * RCAP + i] = cols[i];
}

// ---------------- 512x512 transpose ----------------
__global__ void transpose512(const float* __restrict__ in, float* __restrict__ out) {
  __shared__ float tile[32][33];
  int x = blockIdx.x * 32 + threadIdx.x;
  int y0 = blockIdx.y * 32;
  for (int i = threadIdx.y; i < 32; i += 8)
    tile[i][threadIdx.x] = in[(size_t)(y0 + i) * 512 + x];
  __syncthreads();
  int xo = blockIdx.y * 32 + threadIdx.x;
  int yo0 = blockIdx.x * 32;
  for (int i = threadIdx.y; i < 32; i += 8)
    out[(size_t)(yo0 + i) * 512 + xo] = tile[threadIdx.x][i];
}

// ---------------- fp32 SGEMM: C = A[MxK]@B[KxNn] (+bias); tile 64(M)x128(N), BK=16 ----------------
// 256 threads, 4x8 micro-tile, register prefetch. Requires M%64==0, Nn%128==0, K%16==0.
__global__ __launch_bounds__(256) void sgemm64x128(const float* __restrict__ A,
                                                   const float* __restrict__ B,
                                                   const float* __restrict__ bias,
                                                   float* __restrict__ C,
                                                   int M, int Nn, int K, int ldc) {
  __shared__ float As[16][68];   // transposed A tile, padded (2-way max)
  __shared__ float Bs[16][132];  // padded (2-way max)
  const int tid = threadIdx.x;
  const int bm = blockIdx.y * 64, bn = blockIdx.x * 128;
  const int tx = tid & 15, ty = tid >> 4;        // 16x16 thread grid
  const int arow = tid >> 2, acol = (tid & 3) << 2;  // A tile: 64 rows x 16 k
  const int brow = tid >> 4, bcol = (tid & 15) << 2; // B tile: 16 k x 128 cols (x2 spans)
  float acc[4][8];
#pragma unroll
  for (int i = 0; i < 4; ++i)
#pragma unroll
    for (int j = 0; j < 8; ++j) acc[i][j] = 0.f;

  const float* Ap = A + (size_t)(bm + arow) * K + acol;
  const float* Bp = B + (size_t)brow * Nn + bn + bcol;

  float4 av = *(const float4*)(Ap);
  float4 bv0 = *(const float4*)(Bp);
  float4 bv1 = *(const float4*)(Bp + 64);

  for (int k0 = 0; k0 < K; k0 += 16) {
    if (k0) __syncthreads();
    As[acol + 0][arow] = av.x;
    As[acol + 1][arow] = av.y;
    As[acol + 2][arow] = av.z;
    As[acol + 3][arow] = av.w;
    *(float4*)&Bs[brow][bcol] = bv0;
    *(float4*)&Bs[brow][bcol + 64] = bv1;
    __syncthreads();
    int kn = (k0 + 16 < K) ? k0 + 16 : 0;  // wrap: harmless reload on last iter
    av = *(const float4*)(Ap + kn);
    bv0 = *(const float4*)(Bp + (size_t)kn * Nn);
    bv1 = *(const float4*)(Bp + (size_t)kn * Nn + 64);
#pragma unroll
    for (int kk = 0; kk < 16; ++kk) {
      float4 a = *(const float4*)&As[kk][ty << 2];
      float4 b0 = *(const float4*)&Bs[kk][tx << 2];
      float4 b1 = *(const float4*)&Bs[kk][(tx << 2) + 64];
      float ar[4] = {a.x, a.y, a.z, a.w};
      float br[8] = {b0.x, b0.y, b0.z, b0.w, b1.x, b1.y, b1.z, b1.w};
#pragma unroll
      for (int i = 0; i < 4; ++i)
#pragma unroll
        for (int j = 0; j < 8; ++j) acc[i][j] = fmaf(ar[i], br[j], acc[i][j]);
    }
  }
  float4 bias0 = make_float4(0.f, 0.f, 0.f, 0.f), bias1 = bias0;
  if (bias) {
    bias0 = *(const float4*)(bias + bn + (tx << 2));
    bias1 = *(const float4*)(bias + bn + 64 + (tx << 2));
  }
#pragma unroll
  for (int i = 0; i < 4; ++i) {
    int r = bm + (ty << 2) + i;
    float4 o0 = make_float4(acc[i][0] + bias0.x, acc[i][1] + bias0.y,
                            acc[i][2] + bias0.z, acc[i][3] + bias0.w);
    float4 o1 = make_float4(acc[i][4] + bias1.x, acc[i][5] + bias1.y,
                            acc[i][6] + bias1.z, acc[i][7] + bias1.w);
    *(float4*)(C + (size_t)r * ldc + bn + (tx << 2)) = o0;
    *(float4*)(C + (size_t)r * ldc + bn + 64 + (tx << 2)) = o1;
  }
}

// ---------------- Bcat helpers: Bcat[512x1024] = [M | Vw], bcat[1024] = [0 | Vb] ----------------
__global__ void copy_vw(const float* __restrict__ Vw, float* __restrict__ Bcat) {
  int idx = blockIdx.x * 256 + threadIdx.x;  // over 512*128 float4s
  int r = idx >> 7, c = idx & 127;
  ((float4*)(Bcat + (size_t)r * 1024 + 512))[c] = ((const float4*)(Vw + (size_t)r * 512))[c];
}
__global__ void build_bcat(const float* __restrict__ Vb, float* __restrict__ bcat) {
  int i = blockIdx.x * 256 + threadIdx.x;
  bcat[i] = (i < 512) ? 0.f : Vb[i - 512];
}

// ---------------- rank-1 bias helpers: u = Qw@Kb, w = Kw@Qb, c = Qb.Kb ----------------
__global__ __launch_bounds__(64) void bias_prep(const float* __restrict__ Qw, const float* __restrict__ Kw,
                                                const float* __restrict__ Qb, const float* __restrict__ Kb,
                                                float* __restrict__ u, float* __restrict__ w,
                                                float* __restrict__ cbuf) {
  int k = blockIdx.x;
  int lane = threadIdx.x;
  if (k == NHID) {
    float s = 0.f;
    for (int j = lane; j < NHID; j += 64) s = fmaf(Qb[j], Kb[j], s);
#pragma unroll
    for (int o = 32; o > 0; o >>= 1) s += __shfl_down(s, o, 64);
    if (lane == 0) cbuf[0] = s;
    return;
  }
  float su = 0.f, sw = 0.f;
  for (int j = lane; j < NHID; j += 64) {
    su = fmaf(Qw[(size_t)k * NHID + j], Kb[j], su);
    sw = fmaf(Kw[(size_t)k * NHID + j], Qb[j], sw);
  }
#pragma unroll
  for (int o = 32; o > 0; o >>= 1) { su += __shfl_down(su, o, 64); sw += __shfl_down(sw, o, 64); }
  if (lane == 0) { u[k] = su; w[k] = sw; }
}

// ---------------- h = relu(adj @ xW + b1): 128 thr/row, float4, edge-unroll x4 ----------------
__global__ __launch_bounds__(128) void spmm_bias_relu(const float* __restrict__ xW,
                                                      const int* __restrict__ colidx,
                                                      const int* __restrict__ deg,
                                                      const float* __restrict__ bias,
                                                      float* __restrict__ h) {
  int row = blockIdx.x;
  int d = deg[row];
  __shared__ int scols[RCAP];
  int t = threadIdx.x;
  for (int i = t; i < d; i += 128) scols[i] = colidx[(size_t)row * RCAP + i];
  __syncthreads();
  float4 acc = make_float4(0.f, 0.f, 0.f, 0.f);
  int e = 0;
  for (; e + 4 <= d; e += 4) {
    int c0 = scols[e], c1 = scols[e + 1], c2 = scols[e + 2], c3 = scols[e + 3];
    float4 v0 = ((const float4*)(xW + (size_t)c0 * NHID))[t];
    float4 v1 = ((const float4*)(xW + (size_t)c1 * NHID))[t];
    float4 v2 = ((const float4*)(xW + (size_t)c2 * NHID))[t];
    float4 v3 = ((const float4*)(xW + (size_t)c3 * NHID))[t];
    acc.x += (v0.x + v1.x) + (v2.x + v3.x);
    acc.y += (v0.y + v1.y) + (v2.y + v3.y);
    acc.z += (v0.z + v1.z) + (v2.z + v3.z);
    acc.w += (v0.w + v1.w) + (v2.w + v3.w);
  }
  for (; e < d; ++e) {
    float4 v = ((const float4*)(xW + (size_t)scols[e] * NHID))[t];
    acc.x += v.x; acc.y += v.y; acc.z += v.z; acc.w += v.w;
  }
  float4 bv = ((const float4*)bias)[t];
  float4 o = make_float4(fmaxf(acc.x + bv.x, 0.f), fmaxf(acc.y + bv.y, 0.f),
                         fmaxf(acc.z + bv.z, 0.f), fmaxf(acc.w + bv.w, 0.f));
  ((float4*)(h + (size_t)row * NHID))[t] = o;
}

// ---------------- a_i = h_i.u, b_i = h_i.w (one wave per row) ----------------
__global__ __launch_bounds__(256) void dual_matvec(const float* __restrict__ h, const float* __restrict__ u,
                                                   const float* __restrict__ w, float* __restrict__ a_vec,
                                                   float* __restrict__ b_vec) {
  int t = threadIdx.x;
  int wv = t >> 6, lane = t & 63;
  int row = blockIdx.x * 4 + wv;
  const float2* hr = (const float2*)(h + (size_t)row * NHID);
  const float2* ur = (const float2*)u;
  const float2* wr = (const float2*)w;
  float sa = 0.f, sb = 0.f;
  for (int i = lane; i < NHID / 2; i += 64) {
    float2 hv = hr[i], uv = ur[i], wv2 = wr[i];
    sa = fmaf(hv.x, uv.x, sa); sa = fmaf(hv.y, uv.y, sa);
    sb = fmaf(hv.x, wv2.x, sb); sb = fmaf(hv.y, wv2.y, sb);
  }
#pragma unroll
  for (int o = 32; o > 0; o >>= 1) { sa += __shfl_down(sa, o, 64); sb += __shfl_down(sb, o, 64); }
  if (lane == 0) { a_vec[row] = sa; b_vec[row] = sb; }
}

// ---------------- edge scores + closed-form full-row softmax ----------------
// One wave per row (4 rows/block). Quarter-wave (16 lanes) per edge, 4 edges in flight.
// s_ij = G_i . h_j + a_i + b_j + c ; background (masked) entries = 0 handled in closed form.
__global__ __launch_bounds__(256) void edge_softmax2(const float* __restrict__ G, int ldg,
                                                     const float* __restrict__ h,
                                                     const int* __restrict__ colidx, const int* __restrict__ deg,
                                                     const float* __restrict__ a_vec, const float* __restrict__ b_vec,
                                                     const float* __restrict__ cbuf,
                                                     float* __restrict__ edge_w, float* __restrict__ row_c) {
  __shared__ float gs[4][NHID];
  __shared__ int scols[4][RCAP];
  __shared__ float sb[4][RCAP];
  __shared__ float sv[4][RCAP];
  int t = threadIdx.x, wv = t >> 6, lane = t & 63;
  int row = blockIdx.x * 4 + wv;
  int d = deg[row];
  // stage G row (float4 x2) and columns (+ gathered b_vec)
  const float4* gr = (const float4*)(G + (size_t)row * ldg);
  ((float4*)gs[wv])[lane] = gr[lane];
  ((float4*)gs[wv])[64 + lane] = gr[64 + lane];
  for (int i = lane; i < d; i += 64) {
    int c = colidx[(size_t)row * RCAP + i];
    scols[wv][i] = c;
    sb[wv][i] = b_vec[c];
  }
  __syncthreads();
  float ai = a_vec[row] + cbuf[0];
  int q = lane >> 4, u = lane & 15;
  const float4* gq = (const float4*)gs[wv] + u;
  for (int e0 = 0; e0 < d; e0 += 4) {
    int e = e0 + q;
    bool act = e < d;
    int col = act ? scols[wv][e] : 0;
    const float4* hr = (const float4*)(h + (size_t)col * NHID) + u;
    float s_a = 0.f, s_b = 0.f;
#pragma unroll
    for (int it = 0; it < 8; it += 2) {
      float4 h0 = hr[it * 16], g0 = gq[it * 16];
      float4 h1 = hr[(it + 1) * 16], g1 = gq[(it + 1) * 16];
      s_a = fmaf(h0.x, g0.x, s_a); s_a = fmaf(h0.y, g0.y, s_a);
      s_a = fmaf(h0.z, g0.z, s_a); s_a = fmaf(h0.w, g0.w, s_a);
      s_b = fmaf(h1.x, g1.x, s_b); s_b = fmaf(h1.y, g1.y, s_b);
      s_b = fmaf(h1.z, g1.z, s_b); s_b = fmaf(h1.w, g1.w, s_b);
    }
    float s = s_a + s_b;
    s += __shfl_down(s, 8, 16);
    s += __shfl_down(s, 4, 16);
    s += __shfl_down(s, 2, 16);
    s += __shfl_down(s, 1, 16);
    if (u == 0 && act) sv[wv][e] = s + ai + sb[wv][e];
  }
  // per-wave softmax over sv[0..d) plus implicit background score 0
  float m = 0.f;
  for (int i = lane; i < d; i += 64) m = fmaxf(m, sv[wv][i]);
#pragma unroll
  for (int o = 32; o > 0; o >>= 1) m = fmaxf(m, __shfl_xor(m, o, 64));
  float ssum = 0.f;
  for (int i = lane; i < d; i += 64) {
    float ex = expf(sv[wv][i] - m);
    sv[wv][i] = ex;
    ssum += ex;
  }
#pragma unroll
  for (int o = 32; o > 0; o >>= 1) ssum += __shfl_xor(ssum, o, 64);
  float denom = ssum + (float)(N_NODES - d) * expf(-m);
  float inv = 1.f / denom;
  for (int i = lane; i < d; i += 64) edge_w[(size_t)row * RCAP + i] = sv[wv][i] * inv;
  if (lane == 0) row_c[row] = expf(-m) * inv;
}

// ---------------- T = colsum(Vh) ----------------
__global__ void zero_vec(float* __restrict__ T) { T[threadIdx.x] = 0.f; }

__global__ __launch_bounds__(256) void colsum_atomic(const float* __restrict__ Vh, int ldv,
                                                     float* __restrict__ T) {
  int t = threadIdx.x;
  int r0 = blockIdx.x * 128;
  float2 s = make_float2(0.f, 0.f);
  for (int r = 0; r < 128; ++r) {
    float2 v = ((const float2*)(Vh + (size_t)(r0 + r) * ldv))[t];
    s.x += v.x;
    s.y += v.y;
  }
  atomicAdd(&T[2 * t], s.x);
  atomicAdd(&T[2 * t + 1], s.y);
}

// ---------------- X_tilde = sum_edges (w-c)*Vh[col] + c*T, then LayerNorm ----------------
__global__ __launch_bounds__(128) void aggregate_ln(const float* __restrict__ Vh, int ldv,
                                                    const int* __restrict__ colidx,
                                                    const int* __restrict__ deg, const float* __restrict__ edge_w,
                                                    const float* __restrict__ row_c, const float* __restrict__ T,
                                                    const float* __restrict__ g, const float* __restrict__ b,
                                                    float* __restrict__ Xt) {
  int row = blockIdx.x;
  int d = deg[row];
  float ci = row_c[row];
  __shared__ int scols[RCAP];
  __shared__ float sw[RCAP];
  __shared__ float red1[2], red2[2];
  int t = threadIdx.x;
  for (int i = t; i < d; i += 128) {
    scols[i] = colidx[(size_t)row * RCAP + i];
    sw[i] = edge_w[(size_t)row * RCAP + i] - ci;
  }
  __syncthreads();
  float4 acc = make_float4(0.f, 0.f, 0.f, 0.f);
  int e = 0;
  for (; e + 4 <= d; e += 4) {
    int c0 = scols[e], c1 = scols[e + 1], c2 = scols[e + 2], c3 = scols[e + 3];
    float w0 = sw[e], w1 = sw[e + 1], w2 = sw[e + 2], w3 = sw[e + 3];
    float4 v0 = ((const float4*)(Vh + (size_t)c0 * ldv))[t];
    float4 v1 = ((const float4*)(Vh + (size_t)c1 * ldv))[t];
    float4 v2 = ((const float4*)(Vh + (size_t)c2 * ldv))[t];
    float4 v3 = ((const float4*)(Vh + (size_t)c3 * ldv))[t];
    acc.x = fmaf(w0, v0.x, fmaf(w1, v1.x, fmaf(w2, v2.x, fmaf(w3, v3.x, acc.x))));
    acc.y = fmaf(w0, v0.y, fmaf(w1, v1.y, fmaf(w2, v2.y, fmaf(w3, v3.y, acc.y))));
    acc.z = fmaf(w0, v0.z, fmaf(w1, v1.z, fmaf(w2, v2.z, fmaf(w3, v3.z, acc.z))));
    acc.w = fmaf(w0, v0.w, fmaf(w1, v1.w, fmaf(w2, v2.w, fmaf(w3, v3.w, acc.w))));
  }
  for (; e < d; ++e) {
    float wgt = sw[e];
    float4 v = ((const float4*)(Vh + (size_t)scols[e] * ldv))[t];
    acc.x = fmaf(wgt, v.x, acc.x); acc.y = fmaf(wgt, v.y, acc.y);
    acc.z = fmaf(wgt, v.z, acc.z); acc.w = fmaf(wgt, v.w, acc.w);
  }
  float4 tv = ((const float4*)T)[t];
  acc.x = fmaf(ci, tv.x, acc.x); acc.y = fmaf(ci, tv.y, acc.y);
  acc.z = fmaf(ci, tv.z, acc.z); acc.w = fmaf(ci, tv.w, acc.w);
  // LayerNorm over 512 elems held by 128 threads (2 waves)
  float s1 = (acc.x + acc.y) + (acc.z + acc.w);
  float s2 = (acc.x * acc.x + acc.y * acc.y) + (acc.z * acc.z + acc.w * acc.w);
#pragma unroll
  for (int o = 32; o > 0; o >>= 1) { s1 += __shfl_xor(s1, o, 64); s2 += __shfl_xor(s2, o, 64); }
  int wv = t >> 6, lane = t & 63;
  if (lane == 0) { red1[wv] = s1; red2[wv] = s2; }
  __syncthreads();
  s1 = red1[0] + red1[1];
  s2 = red2[0] + red2[1];
  float mu = s1 * (1.f / NHID);
  float var = s2 * (1.f / NHID) - mu * mu;
  float rstd = rsqrtf(var + 1e-5f);
  float4 gv = ((const float4*)g)[t];
  float4 bv = ((const float4*)b)[t];
  float4 o;
  o.x = (acc.x - mu) * rstd * gv.x + bv.x;
  o.y = (acc.y - mu) * rstd * gv.y + bv.y;
  o.z = (acc.z - mu) * rstd * gv.z + bv.z;
  o.w = (acc.w - mu) * rstd * gv.w + bv.w;
  ((float4*)(Xt + (size_t)row * NHID))[t] = o;
}

// ---------------- Y = Xt @ W2 (512 -> 8), one wave per row ----------------
__global__ __launch_bounds__(256) void xt_w2(const float* __restrict__ Xt, const float* __restrict__ W2,
                                             float* __restrict__ Y) {
  __shared__ float w2s[NHID * NCLASS];
  int t = threadIdx.x;
  for (int i = t; i < NHID * NCLASS; i += 256) w2s[i] = W2[i];
  __syncthreads();
  int wv = t >> 6, lane = t & 63;
  int row = blockIdx.x * 4 + wv;
  const float4* xr = (const float4*)(Xt + (size_t)row * NHID);
  float4 x0 = xr[lane * 2], x1 = xr[lane * 2 + 1];
  float xv[8] = {x0.x, x0.y, x0.z, x0.w, x1.x, x1.y, x1.z, x1.w};
  float acc[NCLASS];
#pragma unroll
  for (int c = 0; c < NCLASS; ++c) acc[c] = 0.f;
#pragma unroll
  for (int kk = 0; kk < 8; ++kk) {
    int k = lane * 8 + kk;
#pragma unroll
    for (int c = 0; c < NCLASS; ++c) acc[c] = fmaf(xv[kk], w2s[k * NCLASS + c], acc[c]);
  }
#pragma unroll
  for (int c = 0; c < NCLASS; ++c)
#pragma unroll
    for (int o = 32; o > 0; o >>= 1) acc[c] += __shfl_down(acc[c], o, 64);
  if (lane == 0) {
    *(float4*)(Y + (size_t)row * NCLASS) = make_float4(acc[0], acc[1], acc[2], acc[3]);
    *(float4*)(Y + (size_t)row * NCLASS + 4) = make_float4(acc[4], acc[5], acc[6], acc[7]);
  }
}

// ---------------- z = adj @ Y + b2, softmax over 8 classes ----------------
__global__ __launch_bounds__(256) void final_spmm_softmax(const float* __restrict__ Y,
                                                          const int* __restrict__ colidx,
                                                          const int* __restrict__ deg,
                                                          const float* __restrict__ b2,
                                                          float* __restrict__ out) {
  int t = threadIdx.x;
  int wv = t >> 6, lane = t & 63;
  int row = blockIdx.x * 4 + wv;
  int d = deg[row];
  const int* cols = colidx + (size_t)row * RCAP;
  float acc[8];
#pragma unroll
  for (int c = 0; c < 8; ++c) acc[c] = 0.f;
  for (int e = lane; e < d; e += 64) {
    int col = cols[e];
    const float4* yr = (const float4*)(Y + (size_t)col * 8);
    float4 y0 = yr[0], y1 = yr[1];
    acc[0] += y0.x; acc[1] += y0.y; acc[2] += y0.z; acc[3] += y0.w;
    acc[4] += y1.x; acc[5] += y1.y; acc[6] += y1.z; acc[7] += y1.w;
  }
#pragma unroll
  for (int c = 0; c < 8; ++c)
#pragma unroll
    for (int o = 32; o > 0; o >>= 1) acc[c] += __shfl_down(acc[c], o, 64);
  if (lane == 0) {
    float z[8];
    float m = -1e30f;
#pragma unroll
    for (int c = 0; c < 8; ++c) { z[c] = acc[c] + b2[c]; m = fmaxf(m, z[c]); }
    float s = 0.f;
#pragma unroll
    for (int c = 0; c < 8; ++c) { z[c] = expf(z[c] - m); s += z[c]; }
    float inv = 1.f / s;
    *(float4*)(out + (size_t)row * 8) = make_float4(z[0] * inv, z[1] * inv, z[2] * inv, z[3] * inv);
    *(float4*)(out + (size_t)row * 8 + 4) = make_float4(z[4] * inv, z[5] * inv, z[6] * inv, z[7] * inv);
  }
}

extern "C" void kernel_launch(void* const* d_in, const int* in_sizes, int n_in,
                              void* d_out, int out_size, void* d_ws, size_t ws_size,
                              hipStream_t stream) {
  const float* adj = (const float*)d_in[0];
  const float* x = (const float*)d_in[1];
  const float* W1 = (const float*)d_in[2];
  const float* b1 = (const float*)d_in[3];
  const float* Qw = (const float*)d_in[4];
  const float* Qb = (const float*)d_in[5];
  const float* Kw = (const float*)d_in[6];
  const float* Kb = (const float*)d_in[7];
  const float* Vw = (const float*)d_in[8];
  const float* Vb = (const float*)d_in[9];
  const float* ln_g = (const float*)d_in[10];
  const float* ln_b = (const float*)d_in[11];
  const float* W2 = (const float*)d_in[12];
  const float* b2 = (const float*)d_in[13];
  float* out = (float*)d_out;

  char* ws = (char*)d_ws;
  size_t off = 0;
  auto alloc = [&](size_t bytes) -> void* {
    void* p = ws + off;
    off = (off + bytes + 255) & ~(size_t)255;
    return p;
  };
  int* colidx = (int*)alloc((size_t)N_NODES * RCAP * 4);
  int* deg = (int*)alloc((size_t)N_NODES * 4);
  float* bufA = (float*)alloc((size_t)N_NODES * NHID * 4);   // xW
  float* bufB = (float*)alloc((size_t)N_NODES * NHID * 4);   // h, then X_tilde
  float* GVh = (float*)alloc((size_t)N_NODES * 1024 * 4);    // [G | Vh], row stride 1024
  float* KwT = (float*)alloc((size_t)512 * 512 * 4);
  float* Bcat = (float*)alloc((size_t)512 * 1024 * 4);       // [M | Vw]
  float* bcat = (float*)alloc((size_t)1024 * 4);
  float* edge_w = (float*)alloc((size_t)N_NODES * RCAP * 4);
  float* row_c = (float*)alloc((size_t)N_NODES * 4);
  float* a_vec = (float*)alloc((size_t)N_NODES * 4);
  float* b_vec = (float*)alloc((size_t)N_NODES * 4);
  float* u_vec = (float*)alloc((size_t)NHID * 4);
  float* w_vec = (float*)alloc((size_t)NHID * 4);
  float* cbuf = (float*)alloc(256);
  float* T = (float*)alloc((size_t)NHID * 4);
  float* Y = (float*)alloc((size_t)N_NODES * NCLASS * 4);
  (void)in_sizes; (void)n_in; (void)out_size; (void)ws_size;

  // 1) sparse structure from dense adj
  build_ell<<<N_NODES, 256, 0, stream>>>(adj, colidx, deg);
  // 2) Bcat = [Qw@Kw^T | Vw]; bcat = [0 | Vb]; rank-1 bias terms
  transpose512<<<dim3(16, 16), dim3(32, 8), 0, stream>>>(Kw, KwT);
  bias_prep<<<NHID + 1, 64, 0, stream>>>(Qw, Kw, Qb, Kb, u_vec, w_vec, cbuf);
  sgemm64x128<<<dim3(4, 8), 256, 0, stream>>>(Qw, KwT, nullptr, Bcat, 512, 512, 512, 1024);
  copy_vw<<<256, 256, 0, stream>>>(Vw, Bcat);
  build_bcat<<<4, 256, 0, stream>>>(Vb, bcat);
  // 3) xW = x @ W1 ; h = relu(adj @ xW + b1)
  sgemm64x128<<<dim3(4, 128), 256, 0, stream>>>(x, W1, nullptr, bufA, N_NODES, NHID, NFEAT, NHID);
  spmm_bias_relu<<<N_NODES, 128, 0, stream>>>(bufA, colidx, deg, b1, bufB);
  // 4) [G | Vh] = h @ Bcat (+[0|Vb]) ; a,b vectors
  sgemm64x128<<<dim3(8, 128), 256, 0, stream>>>(bufB, Bcat, bcat, GVh, N_NODES, 1024, NHID, 1024);
  dual_matvec<<<N_NODES / 4, 256, 0, stream>>>(bufB, u_vec, w_vec, a_vec, b_vec);
  // 5) masked scores + full-row softmax (closed-form background)
  edge_softmax2<<<N_NODES / 4, 256, 0, stream>>>(GVh, 1024, bufB, colidx, deg, a_vec, b_vec, cbuf,
                                                 edge_w, row_c);
  // 6) T = colsum(Vh); X_tilde (+ LayerNorm) -> bufB
  zero_vec<<<1, 512, 0, stream>>>(T);
  colsum_atomic<<<64, 256, 0, stream>>>(GVh + 512, 1024, T);
  aggregate_ln<<<N_NODES, 128, 0, stream>>>(GVh + 512, 1024, colidx, deg, edge_w, row_c, T, ln_g, ln_b, bufB);
  // 7) Y = X_tilde @ W2 ; z = adj @ Y + b2 ; softmax
  xt_w2<<<N_NODES / 4, 256, 0, stream>>>(bufB, W2, Y);
  final_spmm_softmax<<<N_NODES / 4, 256, 0, stream>>>(Y, colidx, deg, b2, out);
}

// Round 3
// 850.741 us; speedup vs baseline: 1.2991x; 1.2184x over previous
//
#include <hip/hip_runtime.h>
#include <math.h>

#define N_NODES 8192
#define NFEAT 512
#define NHID 512
#define NCLASS 8
#define RCAP 192   // max row degree; Binomial(8192,0.01): mean 82, std 9 -> 192 is ~12 sigma
#define KSPLIT 1536  // 3*512: bf16x3 split-K (AhiBhi + AhiBlo + AloBhi)

// ---------- bf16 split helpers ----------
__device__ inline ushort f2bf(float f) {
  uint32_t u = __float_as_uint(f);
  uint32_t r = u + 0x7fffu + ((u >> 16) & 1u);
  return (ushort)(r >> 16);
}
__device__ inline float bf2f(ushort h) { return __uint_as_float(((uint32_t)h) << 16); }

// ---------------- adjacency: dense 0/1 -> ELL (single 256MB pass) ----------------
__global__ __launch_bounds__(256) void build_ell(const float* __restrict__ adj,
                                                 int* __restrict__ colidx,
                                                 int* __restrict__ deg) {
  int row = blockIdx.x;
  __shared__ int cnt;
  __shared__ int cols[RCAP];
  if (threadIdx.x == 0) cnt = 0;
  __syncthreads();
  const float4* arow = (const float4*)(adj + (size_t)row * N_NODES);
  for (int i = threadIdx.x; i < N_NODES / 4; i += 256) {
    float4 v = arow[i];
    int base = i * 4;
    if (v.x > 0.5f) { int p = atomicAdd(&cnt, 1); if (p < RCAP) cols[p] = base; }
    if (v.y > 0.5f) { int p = atomicAdd(&cnt, 1); if (p < RCAP) cols[p] = base + 1; }
    if (v.z > 0.5f) { int p = atomicAdd(&cnt, 1); if (p < RCAP) cols[p] = base + 2; }
    if (v.w > 0.5f) { int p = atomicAdd(&cnt, 1); if (p < RCAP) cols[p] = base + 3; }
  }
  __syncthreads();
  int d = cnt < RCAP ? cnt : RCAP;
  if (threadIdx.x == 0) deg[row] = d;
  for (int i = threadIdx.x; i < d; i += 256) colidx[(size_t)row * RCAP + i] = cols[i];
}

// ---------------- 512x512 transpose ----------------
__global__ void transpose512(const float* __restrict__ in, float* __restrict__ out) {
  __shared__ float tile[32][33];
  int x = blockIdx.x * 32 + threadIdx.x;
  int y0 = blockIdx.y * 32;
  for (int i = threadIdx.y; i < 32; i += 8)
    tile[i][threadIdx.x] = in[(size_t)(y0 + i) * 512 + x];
  __syncthreads();
  int xo = blockIdx.y * 32 + threadIdx.x;
  int yo0 = blockIdx.x * 32;
  for (int i = threadIdx.y; i < 32; i += 8)
    out[(size_t)(yo0 + i) * 512 + xo] = tile[threadIdx.x][i];
}

// ---------------- fp32 SGEMM (kept for the small 512^3 M = Qw@Kw^T) ----------------
__global__ __launch_bounds__(256) void sgemm64x128(const float* __restrict__ A,
                                                   const float* __restrict__ B,
                                                   const float* __restrict__ bias,
                                                   float* __restrict__ C,
                                                   int M, int Nn, int K, int ldc) {
  __shared__ float As[16][68];
  __shared__ float Bs[16][132];
  const int tid = threadIdx.x;
  const int bm = blockIdx.y * 64, bn = blockIdx.x * 128;
  const int tx = tid & 15, ty = tid >> 4;
  const int arow = tid >> 2, acol = (tid & 3) << 2;
  const int brow = tid >> 4, bcol = (tid & 15) << 2;
  float acc[4][8];
#pragma unroll
  for (int i = 0; i < 4; ++i)
#pragma unroll
    for (int j = 0; j < 8; ++j) acc[i][j] = 0.f;
  const float* Ap = A + (size_t)(bm + arow) * K + acol;
  const float* Bp = B + (size_t)brow * Nn + bn + bcol;
  float4 av = *(const float4*)(Ap);
  float4 bv0 = *(const float4*)(Bp);
  float4 bv1 = *(const float4*)(Bp + 64);
  for (int k0 = 0; k0 < K; k0 += 16) {
    if (k0) __syncthreads();
    As[acol + 0][arow] = av.x;
    As[acol + 1][arow] = av.y;
    As[acol + 2][arow] = av.z;
    As[acol + 3][arow] = av.w;
    *(float4*)&Bs[brow][bcol] = bv0;
    *(float4*)&Bs[brow][bcol + 64] = bv1;
    __syncthreads();
    int kn = (k0 + 16 < K) ? k0 + 16 : 0;
    av = *(const float4*)(Ap + kn);
    bv0 = *(const float4*)(Bp + (size_t)kn * Nn);
    bv1 = *(const float4*)(Bp + (size_t)kn * Nn + 64);
#pragma unroll
    for (int kk = 0; kk < 16; ++kk) {
      float4 a = *(const float4*)&As[kk][ty << 2];
      float4 b0 = *(const float4*)&Bs[kk][tx << 2];
      float4 b1 = *(const float4*)&Bs[kk][(tx << 2) + 64];
      float ar[4] = {a.x, a.y, a.z, a.w};
      float br[8] = {b0.x, b0.y, b0.z, b0.w, b1.x, b1.y, b1.z, b1.w};
#pragma unroll
      for (int i = 0; i < 4; ++i)
#pragma unroll
        for (int j = 0; j < 8; ++j) acc[i][j] = fmaf(ar[i], br[j], acc[i][j]);
    }
  }
#pragma unroll
  for (int i = 0; i < 4; ++i) {
    int r = bm + (ty << 2) + i;
    float4 o0 = make_float4(acc[i][0], acc[i][1], acc[i][2], acc[i][3]);
    float4 o1 = make_float4(acc[i][4], acc[i][5], acc[i][6], acc[i][7]);
    if (bias) {
      const float4 z0 = *(const float4*)(bias + bn + (tx << 2));
      const float4 z1 = *(const float4*)(bias + bn + 64 + (tx << 2));
      o0.x += z0.x; o0.y += z0.y; o0.z += z0.z; o0.w += z0.w;
      o1.x += z1.x; o1.y += z1.y; o1.z += z1.z; o1.w += z1.w;
    }
    *(float4*)(C + (size_t)r * ldc + bn + (tx << 2)) = o0;
    *(float4*)(C + (size_t)r * ldc + bn + 64 + (tx << 2)) = o1;
  }
}

// ---------------- split A [Mx512] fp32 -> As [Mx1536] bf16 = [hi | hi | lo] ----------------
__global__ __launch_bounds__(256) void split_a(const float* __restrict__ A, ushort* __restrict__ As) {
  int idx = blockIdx.x * 256 + threadIdx.x;  // over M*128 float4s
  int m = idx >> 7, t = idx & 127;
  float4 v = ((const float4*)(A + (size_t)m * 512))[t];
  ushort4 hi, lo;
  hi.x = f2bf(v.x); hi.y = f2bf(v.y); hi.z = f2bf(v.z); hi.w = f2bf(v.w);
  lo.x = f2bf(v.x - bf2f(hi.x)); lo.y = f2bf(v.y - bf2f(hi.y));
  lo.z = f2bf(v.z - bf2f(hi.z)); lo.w = f2bf(v.w - bf2f(hi.w));
  ushort* row = As + (size_t)m * KSPLIT;
  ((ushort4*)row)[t] = hi;
  ((ushort4*)(row + 512))[t] = hi;
  ((ushort4*)(row + 1024))[t] = lo;
}

// ---------------- split+transpose B [512xNn] fp32 -> Bt [Nn x 1536] bf16 = [hi | lo | hi] ----------------
// (B' = [Bhi; Blo; Bhi] row-concat, so C = Ahi*Bhi + Ahi*Blo + Alo*Bhi)
__global__ __launch_bounds__(256) void split_bt(const float* __restrict__ B, ushort* __restrict__ Bt, int Nn) {
  int idx = blockIdx.x * 256 + threadIdx.x;  // over Nn*384 ushort4s
  int n = idx / 384, t = idx % 384;
  int sec = t >> 7;           // 0:hi 1:lo 2:hi
  int k0 = (t & 127) << 2;
  ushort4 o;
  float f0 = B[(size_t)(k0 + 0) * Nn + n];
  float f1 = B[(size_t)(k0 + 1) * Nn + n];
  float f2 = B[(size_t)(k0 + 2) * Nn + n];
  float f3 = B[(size_t)(k0 + 3) * Nn + n];
  if (sec == 1) {
    o.x = f2bf(f0 - bf2f(f2bf(f0))); o.y = f2bf(f1 - bf2f(f2bf(f1)));
    o.z = f2bf(f2 - bf2f(f2bf(f2))); o.w = f2bf(f3 - bf2f(f2bf(f3)));
  } else {
    o.x = f2bf(f0); o.y = f2bf(f1); o.z = f2bf(f2); o.w = f2bf(f3);
  }
  ((ushort4*)(Bt + (size_t)n * KSPLIT))[t] = o;
}

// same, for Bcat = [Mmat | Vw] columns (Nn = 1024)
__global__ __launch_bounds__(256) void split_bt_cat(const float* __restrict__ Mm, const float* __restrict__ Vw,
                                                    ushort* __restrict__ Bt) {
  int idx = blockIdx.x * 256 + threadIdx.x;  // over 1024*384
  int n = idx / 384, t = idx % 384;
  const float* src = (n < 512) ? (Mm + n) : (Vw + (n - 512));
  int sec = t >> 7;
  int k0 = (t & 127) << 2;
  ushort4 o;
  float f0 = src[(size_t)(k0 + 0) * 512];
  float f1 = src[(size_t)(k0 + 1) * 512];
  float f2 = src[(size_t)(k0 + 2) * 512];
  float f3 = src[(size_t)(k0 + 3) * 512];
  if (sec == 1) {
    o.x = f2bf(f0 - bf2f(f2bf(f0))); o.y = f2bf(f1 - bf2f(f2bf(f1)));
    o.z = f2bf(f2 - bf2f(f2bf(f2))); o.w = f2bf(f3 - bf2f(f2bf(f3)));
  } else {
    o.x = f2bf(f0); o.y = f2bf(f1); o.z = f2bf(f2); o.w = f2bf(f3);
  }
  ((ushort4*)(Bt + (size_t)n * KSPLIT))[t] = o;
}

__global__ void build_bcat(const float* __restrict__ Vb, float* __restrict__ bcat) {
  int i = blockIdx.x * 256 + threadIdx.x;
  bcat[i] = (i < 512) ? 0.f : Vb[i - 512];
}

// ---------------- bf16 MFMA GEMM: C[MxN] = A[MxK] @ Bt[NxK]^T (+bias), fp32 out ----------------
// 128x128 tile, BK=64, 256 thr (4 waves, 2x2 of 64x64), 16x16x32 MFMA, global_load_lds staging.
using frag_ab = __attribute__((ext_vector_type(8))) short;
using frag_cd = __attribute__((ext_vector_type(4))) float;

__global__ __launch_bounds__(256) void mfma_gemm_bt(const ushort* __restrict__ A,
                                                    const ushort* __restrict__ Bt,
                                                    const float* __restrict__ bias,
                                                    float* __restrict__ C,
                                                    int M, int N, int K, int ldc) {
  __shared__ __align__(16) ushort Atile[128 * 64];
  __shared__ __align__(16) ushort Btile[128 * 64];
  const int tid = threadIdx.x;
  const int w = tid >> 6, lane = tid & 63;
  const int m0 = blockIdx.y * 128, n0 = blockIdx.x * 128;
  const int wm = (w >> 1) * 64, wn = (w & 1) * 64;
  const int q = lane >> 4, c = lane & 15;

  frag_cd acc[4][4] = {{{0.f, 0.f, 0.f, 0.f}}};
#pragma unroll
  for (int i = 0; i < 4; ++i)
#pragma unroll
    for (int j = 0; j < 4; ++j) acc[i][j] = (frag_cd){0.f, 0.f, 0.f, 0.f};

  // staging: round r, wave w, lane l -> LDS byte r*4096 + w*1024 + l*16
  //          <-> tile row = r*32 + w*8 + (l>>3), col-byte = (l&7)*16 (rows are 128B = 64 bf16)
  const int srow = (w << 3) + (lane >> 3);
  const int scolb = (lane & 7) << 4;
  const uint8_t* gA = (const uint8_t*)A + ((size_t)(m0 + srow) * K) * 2 + scolb;
  const uint8_t* gB = (const uint8_t*)Bt + ((size_t)(n0 + srow) * K) * 2 + scolb;
  const size_t rowpitch = (size_t)K * 2;

  for (int k0 = 0; k0 < K; k0 += 64) {
    const size_t kb = (size_t)k0 * 2;
#pragma unroll
    for (int r = 0; r < 4; ++r) {
      __builtin_amdgcn_global_load_lds(
          (const __attribute__((address_space(1))) uint32_t*)(gA + (size_t)(r * 32) * rowpitch + kb),
          (__attribute__((address_space(3))) uint32_t*)((uint8_t*)Atile + r * 4096 + w * 1024), 16, 0, 0);
      __builtin_amdgcn_global_load_lds(
          (const __attribute__((address_space(1))) uint32_t*)(gB + (size_t)(r * 32) * rowpitch + kb),
          (__attribute__((address_space(3))) uint32_t*)((uint8_t*)Btile + r * 4096 + w * 1024), 16, 0, 0);
    }
    __syncthreads();
#pragma unroll
    for (int kk = 0; kk < 2; ++kk) {
      frag_ab af[4], bf[4];
#pragma unroll
      for (int i = 0; i < 4; ++i) {
        af[i] = *(const frag_ab*)((const uint8_t*)Atile + (wm + i * 16 + c) * 128 + kk * 64 + q * 16);
        bf[i] = *(const frag_ab*)((const uint8_t*)Btile + (wn + i * 16 + c) * 128 + kk * 64 + q * 16);
      }
#pragma unroll
      for (int i = 0; i < 4; ++i)
#pragma unroll
        for (int j = 0; j < 4; ++j)
          acc[i][j] = __builtin_amdgcn_mfma_f32_16x16x32_bf16(af[i], bf[j], acc[i][j], 0, 0, 0);
    }
    __syncthreads();
  }
  // C/D layout: col = lane&15, row = (lane>>4)*4 + reg
#pragma unroll
  for (int j = 0; j < 4; ++j) {
    int col = n0 + wn + j * 16 + c;
    float bv = bias ? bias[col] : 0.f;
#pragma unroll
    for (int i = 0; i < 4; ++i) {
      int row = m0 + wm + i * 16 + q * 4;
#pragma unroll
      for (int r = 0; r < 4; ++r)
        C[(size_t)(row + r) * ldc + col] = acc[i][j][r] + bv;
    }
  }
}

// ---------------- rank-1 bias helpers: u = Qw@Kb, w = Kw@Qb, c = Qb.Kb ----------------
__global__ __launch_bounds__(64) void bias_prep(const float* __restrict__ Qw, const float* __restrict__ Kw,
                                                const float* __restrict__ Qb, const float* __restrict__ Kb,
                                                float* __restrict__ u, float* __restrict__ w,
                                                float* __restrict__ cbuf) {
  int k = blockIdx.x;
  int lane = threadIdx.x;
  if (k == NHID) {
    float s = 0.f;
    for (int j = lane; j < NHID; j += 64) s = fmaf(Qb[j], Kb[j], s);
#pragma unroll
    for (int o = 32; o > 0; o >>= 1) s += __shfl_down(s, o, 64);
    if (lane == 0) cbuf[0] = s;
    return;
  }
  float su = 0.f, sw = 0.f;
  for (int j = lane; j < NHID; j += 64) {
    su = fmaf(Qw[(size_t)k * NHID + j], Kb[j], su);
    sw = fmaf(Kw[(size_t)k * NHID + j], Qb[j], sw);
  }
#pragma unroll
  for (int o = 32; o > 0; o >>= 1) { su += __shfl_down(su, o, 64); sw += __shfl_down(sw, o, 64); }
  if (lane == 0) { u[k] = su; w[k] = sw; }
}

// ---------------- h = relu(adj @ xW + b1) + fused bf16 hi/lo split of h ----------------
__global__ __launch_bounds__(128) void spmm_bias_relu(const float* __restrict__ xW,
                                                      const int* __restrict__ colidx,
                                                      const int* __restrict__ deg,
                                                      const float* __restrict__ bias,
                                                      float* __restrict__ h,
                                                      ushort* __restrict__ Hs) {
  int row = blockIdx.x;
  int d = deg[row];
  __shared__ int scols[RCAP];
  int t = threadIdx.x;
  for (int i = t; i < d; i += 128) scols[i] = colidx[(size_t)row * RCAP + i];
  __syncthreads();
  float4 acc = make_float4(0.f, 0.f, 0.f, 0.f);
  int e = 0;
  for (; e + 8 <= d; e += 8) {
    float4 v0 = ((const float4*)(xW + (size_t)scols[e + 0] * NHID))[t];
    float4 v1 = ((const float4*)(xW + (size_t)scols[e + 1] * NHID))[t];
    float4 v2 = ((const float4*)(xW + (size_t)scols[e + 2] * NHID))[t];
    float4 v3 = ((const float4*)(xW + (size_t)scols[e + 3] * NHID))[t];
    float4 v4 = ((const float4*)(xW + (size_t)scols[e + 4] * NHID))[t];
    float4 v5 = ((const float4*)(xW + (size_t)scols[e + 5] * NHID))[t];
    float4 v6 = ((const float4*)(xW + (size_t)scols[e + 6] * NHID))[t];
    float4 v7 = ((const float4*)(xW + (size_t)scols[e + 7] * NHID))[t];
    acc.x += ((v0.x + v1.x) + (v2.x + v3.x)) + ((v4.x + v5.x) + (v6.x + v7.x));
    acc.y += ((v0.y + v1.y) + (v2.y + v3.y)) + ((v4.y + v5.y) + (v6.y + v7.y));
    acc.z += ((v0.z + v1.z) + (v2.z + v3.z)) + ((v4.z + v5.z) + (v6.z + v7.z));
    acc.w += ((v0.w + v1.w) + (v2.w + v3.w)) + ((v4.w + v5.w) + (v6.w + v7.w));
  }
  for (; e < d; ++e) {
    float4 v = ((const float4*)(xW + (size_t)scols[e] * NHID))[t];
    acc.x += v.x; acc.y += v.y; acc.z += v.z; acc.w += v.w;
  }
  float4 bv = ((const float4*)bias)[t];
  float4 o = make_float4(fmaxf(acc.x + bv.x, 0.f), fmaxf(acc.y + bv.y, 0.f),
                         fmaxf(acc.z + bv.z, 0.f), fmaxf(acc.w + bv.w, 0.f));
  ((float4*)(h + (size_t)row * NHID))[t] = o;
  ushort4 hi, lo;
  hi.x = f2bf(o.x); hi.y = f2bf(o.y); hi.z = f2bf(o.z); hi.w = f2bf(o.w);
  lo.x = f2bf(o.x - bf2f(hi.x)); lo.y = f2bf(o.y - bf2f(hi.y));
  lo.z = f2bf(o.z - bf2f(hi.z)); lo.w = f2bf(o.w - bf2f(hi.w));
  ushort* hr = Hs + (size_t)row * KSPLIT;
  ((ushort4*)hr)[t] = hi;
  ((ushort4*)(hr + 512))[t] = hi;
  ((ushort4*)(hr + 1024))[t] = lo;
}

// ---------------- a_i = h_i.u, b_i = h_i.w (one wave per row) ----------------
__global__ __launch_bounds__(256) void dual_matvec(const float* __restrict__ h, const float* __restrict__ u,
                                                   const float* __restrict__ w, float* __restrict__ a_vec,
                                                   float* __restrict__ b_vec) {
  int t = threadIdx.x;
  int wv = t >> 6, lane = t & 63;
  int row = blockIdx.x * 4 + wv;
  const float2* hr = (const float2*)(h + (size_t)row * NHID);
  const float2* ur = (const float2*)u;
  const float2* wr = (const float2*)w;
  float sa = 0.f, sb = 0.f;
  for (int i = lane; i < NHID / 2; i += 64) {
    float2 hv = hr[i], uv = ur[i], wv2 = wr[i];
    sa = fmaf(hv.x, uv.x, sa); sa = fmaf(hv.y, uv.y, sa);
    sb = fmaf(hv.x, wv2.x, sb); sb = fmaf(hv.y, wv2.y, sb);
  }
#pragma unroll
  for (int o = 32; o > 0; o >>= 1) { sa += __shfl_down(sa, o, 64); sb += __shfl_down(sb, o, 64); }
  if (lane == 0) { a_vec[row] = sa; b_vec[row] = sb; }
}

// ---------------- T = colsum(Vh) ----------------
__global__ void zero_vec(float* __restrict__ T) { T[threadIdx.x] = 0.f; }

__global__ __launch_bounds__(256) void colsum_atomic(const float* __restrict__ Vh, int ldv,
                                                     float* __restrict__ T) {
  int t = threadIdx.x;
  int r0 = blockIdx.x * 128;
  float2 s = make_float2(0.f, 0.f);
  for (int r = 0; r < 128; ++r) {
    float2 v = ((const float2*)(Vh + (size_t)(r0 + r) * ldv))[t];
    s.x += v.x;
    s.y += v.y;
  }
  atomicAdd(&T[2 * t], s.x);
  atomicAdd(&T[2 * t + 1], s.y);
}

// ---------------- fused: edge scores -> closed-form softmax -> thresholded aggregate -> LayerNorm ----------------
// One wave per row. s_ij = G_i.h_j + a_i + b_j + c; background (zeros) in closed form.
// Softmax weights are near-one-hot (score sigma ~1e3): only edges with w > 1e-12 are gathered
// (error <= deg*1e-12*|Vh| ~ 1e-9; adaptive - if a row is flat, all edges are gathered).
__global__ __launch_bounds__(256) void edge_softmax_agg(const float* __restrict__ G, int ldg,
                                                        const float* __restrict__ h,
                                                        const float* __restrict__ Vh, int ldv,
                                                        const int* __restrict__ colidx, const int* __restrict__ deg,
                                                        const float* __restrict__ a_vec, const float* __restrict__ b_vec,
                                                        const float* __restrict__ cbuf, const float* __restrict__ T,
                                                        const float* __restrict__ lng, const float* __restrict__ lnb,
                                                        float* __restrict__ Xt) {
  __shared__ float gs[4][NHID];
  __shared__ int scols[4][RCAP];
  __shared__ float sbv[4][RCAP];
  __shared__ float sv[4][RCAP];
  int t = threadIdx.x, wv = t >> 6, lane = t & 63;
  int row = blockIdx.x * 4 + wv;
  int d = deg[row];
  const float4* gr = (const float4*)(G + (size_t)row * ldg);
  ((float4*)gs[wv])[lane] = gr[lane];
  ((float4*)gs[wv])[64 + lane] = gr[64 + lane];
  for (int i = lane; i < d; i += 64) {
    int cc = colidx[(size_t)row * RCAP + i];
    scols[wv][i] = cc;
    sbv[wv][i] = b_vec[cc];
  }
  __syncthreads();
  float ai = a_vec[row] + cbuf[0];
  int q = lane >> 4, u = lane & 15;
  const float4* gq = (const float4*)gs[wv] + u;
  for (int e0 = 0; e0 < d; e0 += 4) {
    int e = e0 + q;
    bool act = e < d;
    int col = act ? scols[wv][e] : 0;
    const float4* hr = (const float4*)(h + (size_t)col * NHID) + u;
    float s_a = 0.f, s_b = 0.f;
#pragma unroll
    for (int it = 0; it < 8; it += 2) {
      float4 h0 = hr[it * 16], g0 = gq[it * 16];
      float4 h1 = hr[(it + 1) * 16], g1 = gq[(it + 1) * 16];
      s_a = fmaf(h0.x, g0.x, s_a); s_a = fmaf(h0.y, g0.y, s_a);
      s_a = fmaf(h0.z, g0.z, s_a); s_a = fmaf(h0.w, g0.w, s_a);
      s_b = fmaf(h1.x, g1.x, s_b); s_b = fmaf(h1.y, g1.y, s_b);
      s_b = fmaf(h1.z, g1.z, s_b); s_b = fmaf(h1.w, g1.w, s_b);
    }
    float s = s_a + s_b;
    s += __shfl_down(s, 8, 16);
    s += __shfl_down(s, 4, 16);
    s += __shfl_down(s, 2, 16);
    s += __shfl_down(s, 1, 16);
    if (u == 0 && act) sv[wv][e] = s + ai + sbv[wv][e];
  }
  __syncthreads();
  float m = 0.f;  // background score 0 included in the max
  for (int i = lane; i < d; i += 64) m = fmaxf(m, sv[wv][i]);
#pragma unroll
  for (int o = 32; o > 0; o >>= 1) m = fmaxf(m, __shfl_xor(m, o, 64));
  float ssum = 0.f;
  for (int i = lane; i < d; i += 64) {
    float ex = expf(sv[wv][i] - m);
    sv[wv][i] = ex;
    ssum += ex;
  }
#pragma unroll
  for (int o = 32; o > 0; o >>= 1) ssum += __shfl_xor(ssum, o, 64);
  float em = expf(-m);
  float inv = 1.f / (ssum + (float)(N_NODES - d) * em);
  float ci = em * inv;
  __syncthreads();
  // aggregate: lane owns 8 floats (two float4 at lane*2, lane*2+1)
  float4 a0 = make_float4(0.f, 0.f, 0.f, 0.f), a1 = a0;
  for (int e = 0; e < d; ++e) {
    float we = sv[wv][e] * inv;
    if (we > 1e-12f) {
      const float4* vr = (const float4*)(Vh + (size_t)scols[wv][e] * ldv);
      float4 v0 = vr[lane * 2], v1 = vr[lane * 2 + 1];
      a0.x = fmaf(we, v0.x, a0.x); a0.y = fmaf(we, v0.y, a0.y);
      a0.z = fmaf(we, v0.z, a0.z); a0.w = fmaf(we, v0.w, a0.w);
      a1.x = fmaf(we, v1.x, a1.x); a1.y = fmaf(we, v1.y, a1.y);
      a1.z = fmaf(we, v1.z, a1.z); a1.w = fmaf(we, v1.w, a1.w);
    }
  }
  float4 t0 = ((const float4*)T)[lane * 2], t1 = ((const float4*)T)[lane * 2 + 1];
  a0.x = fmaf(ci, t0.x, a0.x); a0.y = fmaf(ci, t0.y, a0.y);
  a0.z = fmaf(ci, t0.z, a0.z); a0.w = fmaf(ci, t0.w, a0.w);
  a1.x = fmaf(ci, t1.x, a1.x); a1.y = fmaf(ci, t1.y, a1.y);
  a1.z = fmaf(ci, t1.z, a1.z); a1.w = fmaf(ci, t1.w, a1.w);
  // LayerNorm across the wave (512 elems, 8 per lane)
  float s1 = ((a0.x + a0.y) + (a0.z + a0.w)) + ((a1.x + a1.y) + (a1.z + a1.w));
  float s2 = ((a0.x * a0.x + a0.y * a0.y) + (a0.z * a0.z + a0.w * a0.w)) +
             ((a1.x * a1.x + a1.y * a1.y) + (a1.z * a1.z + a1.w * a1.w));
#pragma unroll
  for (int o = 32; o > 0; o >>= 1) { s1 += __shfl_xor(s1, o, 64); s2 += __shfl_xor(s2, o, 64); }
  float mu = s1 * (1.f / NHID);
  float var = s2 * (1.f / NHID) - mu * mu;
  float rstd = rsqrtf(var + 1e-5f);
  float4 g0 = ((const float4*)lng)[lane * 2], g1 = ((const float4*)lng)[lane * 2 + 1];
  float4 b0 = ((const float4*)lnb)[lane * 2], b1 = ((const float4*)lnb)[lane * 2 + 1];
  float4 o0, o1;
  o0.x = (a0.x - mu) * rstd * g0.x + b0.x;
  o0.y = (a0.y - mu) * rstd * g0.y + b0.y;
  o0.z = (a0.z - mu) * rstd * g0.z + b0.z;
  o0.w = (a0.w - mu) * rstd * g0.w + b0.w;
  o1.x = (a1.x - mu) * rstd * g1.x + b1.x;
  o1.y = (a1.y - mu) * rstd * g1.y + b1.y;
  o1.z = (a1.z - mu) * rstd * g1.z + b1.z;
  o1.w = (a1.w - mu) * rstd * g1.w + b1.w;
  float4* xr = (float4*)(Xt + (size_t)row * NHID);
  xr[lane * 2] = o0;
  xr[lane * 2 + 1] = o1;
}

// ---------------- Y = Xt @ W2 (512 -> 8), one wave per row ----------------
__global__ __launch_bounds__(256) void xt_w2(const float* __restrict__ Xt, const float* __restrict__ W2,
                                             float* __restrict__ Y) {
  __shared__ float w2s[NHID * NCLASS];
  int t = threadIdx.x;
  for (int i = t; i < NHID * NCLASS; i += 256) w2s[i] = W2[i];
  __syncthreads();
  int wv = t >> 6, lane = t & 63;
  int row = blockIdx.x * 4 + wv;
  const float4* xr = (const float4*)(Xt + (size_t)row * NHID);
  float4 x0 = xr[lane * 2], x1 = xr[lane * 2 + 1];
  float xv[8] = {x0.x, x0.y, x0.z, x0.w, x1.x, x1.y, x1.z, x1.w};
  float acc[NCLASS];
#pragma unroll
  for (int c = 0; c < NCLASS; ++c) acc[c] = 0.f;
#pragma unroll
  for (int kk = 0; kk < 8; ++kk) {
    int k = lane * 8 + kk;
#pragma unroll
    for (int c = 0; c < NCLASS; ++c) acc[c] = fmaf(xv[kk], w2s[k * NCLASS + c], acc[c]);
  }
#pragma unroll
  for (int c = 0; c < NCLASS; ++c)
#pragma unroll
    for (int o = 32; o > 0; o >>= 1) acc[c] += __shfl_down(acc[c], o, 64);
  if (lane == 0) {
    *(float4*)(Y + (size_t)row * NCLASS) = make_float4(acc[0], acc[1], acc[2], acc[3]);
    *(float4*)(Y + (size_t)row * NCLASS + 4) = make_float4(acc[4], acc[5], acc[6], acc[7]);
  }
}

// ---------------- z = adj @ Y + b2, softmax over 8 classes ----------------
__global__ __launch_bounds__(256) void final_spmm_softmax(const float* __restrict__ Y,
                                                          const int* __restrict__ colidx,
                                                          const int* __restrict__ deg,
                                                          const float* __restrict__ b2,
                                                          float* __restrict__ out) {
  int t = threadIdx.x;
  int wv = t >> 6, lane = t & 63;
  int row = blockIdx.x * 4 + wv;
  int d = deg[row];
  const int* cols = colidx + (size_t)row * RCAP;
  float acc[8];
#pragma unroll
  for (int c = 0; c < 8; ++c) acc[c] = 0.f;
  for (int e = lane; e < d; e += 64) {
    int col = cols[e];
    const float4* yr = (const float4*)(Y + (size_t)col * 8);
    float4 y0 = yr[0], y1 = yr[1];
    acc[0] += y0.x; acc[1] += y0.y; acc[2] += y0.z; acc[3] += y0.w;
    acc[4] += y1.x; acc[5] += y1.y; acc[6] += y1.z; acc[7] += y1.w;
  }
#pragma unroll
  for (int c = 0; c < 8; ++c)
#pragma unroll
    for (int o = 32; o > 0; o >>= 1) acc[c] += __shfl_down(acc[c], o, 64);
  if (lane == 0) {
    float z[8];
    float m = -1e30f;
#pragma unroll
    for (int c = 0; c < 8; ++c) { z[c] = acc[c] + b2[c]; m = fmaxf(m, z[c]); }
    float s = 0.f;
#pragma unroll
    for (int c = 0; c < 8; ++c) { z[c] = expf(z[c] - m); s += z[c]; }
    float inv = 1.f / s;
    *(float4*)(out + (size_t)row * 8) = make_float4(z[0] * inv, z[1] * inv, z[2] * inv, z[3] * inv);
    *(float4*)(out + (size_t)row * 8 + 4) = make_float4(z[4] * inv, z[5] * inv, z[6] * inv, z[7] * inv);
  }
}

extern "C" void kernel_launch(void* const* d_in, const int* in_sizes, int n_in,
                              void* d_out, int out_size, void* d_ws, size_t ws_size,
                              hipStream_t stream) {
  const float* adj = (const float*)d_in[0];
  const float* x = (const float*)d_in[1];
  const float* W1 = (const float*)d_in[2];
  const float* b1 = (const float*)d_in[3];
  const float* Qw = (const float*)d_in[4];
  const float* Qb = (const float*)d_in[5];
  const float* Kw = (const float*)d_in[6];
  const float* Kb = (const float*)d_in[7];
  const float* Vw = (const float*)d_in[8];
  const float* Vb = (const float*)d_in[9];
  const float* ln_g = (const float*)d_in[10];
  const float* ln_b = (const float*)d_in[11];
  const float* W2 = (const float*)d_in[12];
  const float* b2 = (const float*)d_in[13];
  float* out = (float*)d_out;

  char* ws = (char*)d_ws;
  size_t off = 0;
  auto alloc = [&](size_t bytes) -> void* {
    void* p = ws + off;
    off = (off + bytes + 255) & ~(size_t)255;
    return p;
  };
  int* colidx = (int*)alloc((size_t)N_NODES * RCAP * 4);
  int* deg = (int*)alloc((size_t)N_NODES * 4);
  float* bufA = (float*)alloc((size_t)N_NODES * NHID * 4);       // xW, then Xt
  float* bufB = (float*)alloc((size_t)N_NODES * NHID * 4);       // h
  float* GVh = (float*)alloc((size_t)N_NODES * 1024 * 4);        // [G | Vh], stride 1024
  ushort* Xs = (ushort*)alloc((size_t)N_NODES * KSPLIT * 2);     // split x
  ushort* Hs = (ushort*)alloc((size_t)N_NODES * KSPLIT * 2);     // split h
  ushort* W1ts = (ushort*)alloc((size_t)512 * KSPLIT * 2);       // split W1^T
  ushort* Bcts = (ushort*)alloc((size_t)1024 * KSPLIT * 2);      // split [M|Vw]^T
  float* KwT = (float*)alloc((size_t)512 * 512 * 4);
  float* Mmat = (float*)alloc((size_t)512 * 512 * 4);
  float* bcat = (float*)alloc((size_t)1024 * 4);
  float* a_vec = (float*)alloc((size_t)N_NODES * 4);
  float* b_vec = (float*)alloc((size_t)N_NODES * 4);
  float* u_vec = (float*)alloc((size_t)NHID * 4);
  float* w_vec = (float*)alloc((size_t)NHID * 4);
  float* cbuf = (float*)alloc(256);
  float* T = (float*)alloc((size_t)NHID * 4);
  float* Y = (float*)alloc((size_t)N_NODES * NCLASS * 4);
  (void)in_sizes; (void)n_in; (void)out_size; (void)ws_size;

  // 1) sparse structure from dense adj
  build_ell<<<N_NODES, 256, 0, stream>>>(adj, colidx, deg);
  // 2) M = Qw@Kw^T (fp32, small); rank-1 bias terms
  transpose512<<<dim3(16, 16), dim3(32, 8), 0, stream>>>(Kw, KwT);
  bias_prep<<<NHID + 1, 64, 0, stream>>>(Qw, Kw, Qb, Kb, u_vec, w_vec, cbuf);
  sgemm64x128<<<dim3(4, 8), 256, 0, stream>>>(Qw, KwT, nullptr, Mmat, 512, 512, 512, 512);
  // 3) bf16x3 splits for x and W1^T; xW = x@W1 via MFMA
  split_a<<<(N_NODES * 128) / 256, 256, 0, stream>>>(x, Xs);
  split_bt<<<(512 * 384) / 256, 256, 0, stream>>>(W1, W1ts, 512);
  mfma_gemm_bt<<<dim3(4, 64), 256, 0, stream>>>(Xs, W1ts, nullptr, bufA, N_NODES, 512, KSPLIT, 512);
  // 4) h = relu(adj@xW + b1), fused hi/lo split
  spmm_bias_relu<<<N_NODES, 128, 0, stream>>>(bufA, colidx, deg, b1, bufB, Hs);
  // 5) [G | Vh] = h @ [M | Vw] (+[0|Vb]) via MFMA
  split_bt_cat<<<(1024 * 384) / 256, 256, 0, stream>>>(Mmat, Vw, Bcts);
  build_bcat<<<4, 256, 0, stream>>>(Vb, bcat);
  mfma_gemm_bt<<<dim3(8, 64), 256, 0, stream>>>(Hs, Bcts, bcat, GVh, N_NODES, 1024, KSPLIT, 1024);
  dual_matvec<<<N_NODES / 4, 256, 0, stream>>>(bufB, u_vec, w_vec, a_vec, b_vec);
  // 6) T = colsum(Vh)
  zero_vec<<<1, 512, 0, stream>>>(T);
  colsum_atomic<<<64, 256, 0, stream>>>(GVh + 512, 1024, T);
  // 7) fused scores + softmax + thresholded aggregate + LayerNorm -> Xt (bufA)
  edge_softmax_agg<<<N_NODES / 4, 256, 0, stream>>>(GVh, 1024, bufB, GVh + 512, 1024, colidx, deg,
                                                    a_vec, b_vec, cbuf, T, ln_g, ln_b, bufA);
  // 8) Y = Xt @ W2 ; z = adj @ Y + b2 ; softmax
  xt_w2<<<N_NODES / 4, 256, 0, stream>>>(bufA, W2, Y);
  final_spmm_softmax<<<N_NODES / 4, 256, 0, stream>>>(Y, colidx, deg, b2, out);
}

// Round 4
// 812.337 us; speedup vs baseline: 1.3605x; 1.0473x over previous
//
#include <hip/hip_runtime.h>
#include <math.h>

#define N_NODES 8192
#define NFEAT 512
#define NHID 512
#define NCLASS 8
#define RCAP 192     // max row degree; Binomial(8192,0.01): mean 82, std 9 -> 192 is ~12 sigma
#define KB_SPLIT 1536  // B operand: [hi | lo | hi] bf16
#define KA_SPLIT 1024  // A operand: [hi | lo] bf16 (chunk map re-reads hi)
#define NSLICE 8       // gather slices: 1024 rows = 2 MB, L2-resident per XCD

// ---------- bf16 split helpers ----------
__device__ inline ushort f2bf(float f) {
  uint32_t u = __float_as_uint(f);
  uint32_t r = u + 0x7fffu + ((u >> 16) & 1u);
  return (ushort)(r >> 16);
}
__device__ inline float bf2f(ushort h) { return __uint_as_float(((uint32_t)h) << 16); }

// ---------------- adjacency: dense 0/1 -> ELL (single 256MB pass) ----------------
__global__ __launch_bounds__(256) void build_ell(const float* __restrict__ adj,
                                                 int* __restrict__ colidx,
                                                 int* __restrict__ deg) {
  int row = blockIdx.x;
  __shared__ int cnt;
  __shared__ int cols[RCAP];
  if (threadIdx.x == 0) cnt = 0;
  __syncthreads();
  const float4* arow = (const float4*)(adj + (size_t)row * N_NODES);
  for (int i = threadIdx.x; i < N_NODES / 4; i += 256) {
    float4 v = arow[i];
    int base = i * 4;
    if (v.x > 0.5f) { int p = atomicAdd(&cnt, 1); if (p < RCAP) cols[p] = base; }
    if (v.y > 0.5f) { int p = atomicAdd(&cnt, 1); if (p < RCAP) cols[p] = base + 1; }
    if (v.z > 0.5f) { int p = atomicAdd(&cnt, 1); if (p < RCAP) cols[p] = base + 2; }
    if (v.w > 0.5f) { int p = atomicAdd(&cnt, 1); if (p < RCAP) cols[p] = base + 3; }
  }
  __syncthreads();
  int d = cnt < RCAP ? cnt : RCAP;
  if (threadIdx.x == 0) deg[row] = d;
  for (int i = threadIdx.x; i < d; i += 256) colidx[(size_t)row * RCAP + i] = cols[i];
}

// ---------------- 512x512 transpose ----------------
__global__ void transpose512(const float* __restrict__ in, float* __restrict__ out) {
  __shared__ float tile[32][33];
  int x = blockIdx.x * 32 + threadIdx.x;
  int y0 = blockIdx.y * 32;
  for (int i = threadIdx.y; i < 32; i += 8)
    tile[i][threadIdx.x] = in[(size_t)(y0 + i) * 512 + x];
  __syncthreads();
  int xo = blockIdx.y * 32 + threadIdx.x;
  int yo0 = blockIdx.x * 32;
  for (int i = threadIdx.y; i < 32; i += 8)
    out[(size_t)(yo0 + i) * 512 + xo] = tile[threadIdx.x][i];
}

// ---------------- fp32 SGEMM (small 512^3: M = Qw@Kw^T) ----------------
__global__ __launch_bounds__(256) void sgemm64x128(const float* __restrict__ A,
                                                   const float* __restrict__ B,
                                                   float* __restrict__ C,
                                                   int M, int Nn, int K, int ldc) {
  __shared__ float As[16][68];
  __shared__ float Bs[16][132];
  const int tid = threadIdx.x;
  const int bm = blockIdx.y * 64, bn = blockIdx.x * 128;
  const int tx = tid & 15, ty = tid >> 4;
  const int arow = tid >> 2, acol = (tid & 3) << 2;
  const int brow = tid >> 4, bcol = (tid & 15) << 2;
  float acc[4][8];
#pragma unroll
  for (int i = 0; i < 4; ++i)
#pragma unroll
    for (int j = 0; j < 8; ++j) acc[i][j] = 0.f;
  const float* Ap = A + (size_t)(bm + arow) * K + acol;
  const float* Bp = B + (size_t)brow * Nn + bn + bcol;
  float4 av = *(const float4*)(Ap);
  float4 bv0 = *(const float4*)(Bp);
  float4 bv1 = *(const float4*)(Bp + 64);
  for (int k0 = 0; k0 < K; k0 += 16) {
    if (k0) __syncthreads();
    As[acol + 0][arow] = av.x;
    As[acol + 1][arow] = av.y;
    As[acol + 2][arow] = av.z;
    As[acol + 3][arow] = av.w;
    *(float4*)&Bs[brow][bcol] = bv0;
    *(float4*)&Bs[brow][bcol + 64] = bv1;
    __syncthreads();
    int kn = (k0 + 16 < K) ? k0 + 16 : 0;
    av = *(const float4*)(Ap + kn);
    bv0 = *(const float4*)(Bp + (size_t)kn * Nn);
    bv1 = *(const float4*)(Bp + (size_t)kn * Nn + 64);
#pragma unroll
    for (int kk = 0; kk < 16; ++kk) {
      float4 a = *(const float4*)&As[kk][ty << 2];
      float4 b0 = *(const float4*)&Bs[kk][tx << 2];
      float4 b1 = *(const float4*)&Bs[kk][(tx << 2) + 64];
      float ar[4] = {a.x, a.y, a.z, a.w};
      float br[8] = {b0.x, b0.y, b0.z, b0.w, b1.x, b1.y, b1.z, b1.w};
#pragma unroll
      for (int i = 0; i < 4; ++i)
#pragma unroll
        for (int j = 0; j < 8; ++j) acc[i][j] = fmaf(ar[i], br[j], acc[i][j]);
    }
  }
#pragma unroll
  for (int i = 0; i < 4; ++i) {
    int r = bm + (ty << 2) + i;
    *(float4*)(C + (size_t)r * ldc + bn + (tx << 2)) =
        make_float4(acc[i][0], acc[i][1], acc[i][2], acc[i][3]);
    *(float4*)(C + (size_t)r * ldc + bn + 64 + (tx << 2)) =
        make_float4(acc[i][4], acc[i][5], acc[i][6], acc[i][7]);
  }
}

// ---------------- split A [Mx512] fp32 -> [M x 1024] bf16 = [hi | lo] ----------------
__global__ __launch_bounds__(256) void split_a2(const float* __restrict__ A, ushort* __restrict__ As) {
  int idx = blockIdx.x * 256 + threadIdx.x;  // over M*128 float4s
  int m = idx >> 7, t = idx & 127;
  float4 v = ((const float4*)(A + (size_t)m * 512))[t];
  ushort4 hi, lo;
  hi.x = f2bf(v.x); hi.y = f2bf(v.y); hi.z = f2bf(v.z); hi.w = f2bf(v.w);
  lo.x = f2bf(v.x - bf2f(hi.x)); lo.y = f2bf(v.y - bf2f(hi.y));
  lo.z = f2bf(v.z - bf2f(hi.z)); lo.w = f2bf(v.w - bf2f(hi.w));
  ushort* row = As + (size_t)m * KA_SPLIT;
  ((ushort4*)row)[t] = hi;
  ((ushort4*)(row + 512))[t] = lo;
}

// ---------------- split+transpose B [512xNn] fp32 -> Bt [Nn x 1536] bf16 = [hi | lo | hi] ----------------
__global__ __launch_bounds__(256) void split_bt(const float* __restrict__ B, ushort* __restrict__ Bt, int Nn) {
  int idx = blockIdx.x * 256 + threadIdx.x;  // over Nn*384 ushort4s
  int n = idx / 384, t = idx % 384;
  int sec = t >> 7;  // 0:hi 1:lo 2:hi
  int k0 = (t & 127) << 2;
  ushort4 o;
  float f0 = B[(size_t)(k0 + 0) * Nn + n];
  float f1 = B[(size_t)(k0 + 1) * Nn + n];
  float f2 = B[(size_t)(k0 + 2) * Nn + n];
  float f3 = B[(size_t)(k0 + 3) * Nn + n];
  if (sec == 1) {
    o.x = f2bf(f0 - bf2f(f2bf(f0))); o.y = f2bf(f1 - bf2f(f2bf(f1)));
    o.z = f2bf(f2 - bf2f(f2bf(f2))); o.w = f2bf(f3 - bf2f(f2bf(f3)));
  } else {
    o.x = f2bf(f0); o.y = f2bf(f1); o.z = f2bf(f2); o.w = f2bf(f3);
  }
  ((ushort4*)(Bt + (size_t)n * KB_SPLIT))[t] = o;
}

// same, for Bcat = [Mmat | Vw] columns (Nn = 1024)
__global__ __launch_bounds__(256) void split_bt_cat(const float* __restrict__ Mm, const float* __restrict__ Vw,
                                                    ushort* __restrict__ Bt) {
  int idx = blockIdx.x * 256 + threadIdx.x;  // over 1024*384
  int n = idx / 384, t = idx % 384;
  const float* src = (n < 512) ? (Mm + n) : (Vw + (n - 512));
  int sec = t >> 7;
  int k0 = (t & 127) << 2;
  ushort4 o;
  float f0 = src[(size_t)(k0 + 0) * 512];
  float f1 = src[(size_t)(k0 + 1) * 512];
  float f2 = src[(size_t)(k0 + 2) * 512];
  float f3 = src[(size_t)(k0 + 3) * 512];
  if (sec == 1) {
    o.x = f2bf(f0 - bf2f(f2bf(f0))); o.y = f2bf(f1 - bf2f(f2bf(f1)));
    o.z = f2bf(f2 - bf2f(f2bf(f2))); o.w = f2bf(f3 - bf2f(f2bf(f3)));
  } else {
    o.x = f2bf(f0); o.y = f2bf(f1); o.z = f2bf(f2); o.w = f2bf(f3);
  }
  ((ushort4*)(Bt + (size_t)n * KB_SPLIT))[t] = o;
}

__global__ void build_bcat(const float* __restrict__ Vb, float* __restrict__ bcat) {
  int i = blockIdx.x * 256 + threadIdx.x;
  bcat[i] = (i < 512) ? 0.f : Vb[i - 512];
}

// ---------------- bf16x3 MFMA GEMM: C = A[hi|lo,K=1024] @ Bt[hi|lo|hi,K=1536]^T (+bias) ----------------
// chunk map: c in [0,24): A k-off = (c<8?c:c-8)*64  -> AhiBhi + AhiBlo + AloBhi
using frag_ab = __attribute__((ext_vector_type(8))) short;
using frag_cd = __attribute__((ext_vector_type(4))) float;

__global__ __launch_bounds__(256) void mfma_gemm_bt(const ushort* __restrict__ A,
                                                    const ushort* __restrict__ Bt,
                                                    const float* __restrict__ bias,
                                                    float* __restrict__ C,
                                                    int ldc) {
  __shared__ __align__(16) ushort Atile[128 * 64];
  __shared__ __align__(16) ushort Btile[128 * 64];
  const int tid = threadIdx.x;
  const int w = tid >> 6, lane = tid & 63;
  const int m0 = blockIdx.y * 128, n0 = blockIdx.x * 128;
  const int wm = (w >> 1) * 64, wn = (w & 1) * 64;
  const int q = lane >> 4, c16 = lane & 15;

  frag_cd acc[4][4];
#pragma unroll
  for (int i = 0; i < 4; ++i)
#pragma unroll
    for (int j = 0; j < 4; ++j) acc[i][j] = (frag_cd){0.f, 0.f, 0.f, 0.f};

  const int srow = (w << 3) + (lane >> 3);
  const int scolb = (lane & 7) << 4;
  const uint8_t* gA = (const uint8_t*)A + (size_t)(m0 + srow) * (KA_SPLIT * 2) + scolb;
  const uint8_t* gB = (const uint8_t*)Bt + (size_t)(n0 + srow) * (KB_SPLIT * 2) + scolb;

  for (int c = 0; c < 24; ++c) {
    const size_t kaB = (size_t)((c < 8 ? c : c - 8) * 128);
    const size_t kbB = (size_t)(c * 128);
#pragma unroll
    for (int r = 0; r < 4; ++r) {
      __builtin_amdgcn_global_load_lds(
          (const __attribute__((address_space(1))) uint32_t*)(gA + (size_t)(r * 32) * (KA_SPLIT * 2) + kaB),
          (__attribute__((address_space(3))) uint32_t*)((uint8_t*)Atile + r * 4096 + w * 1024), 16, 0, 0);
      __builtin_amdgcn_global_load_lds(
          (const __attribute__((address_space(1))) uint32_t*)(gB + (size_t)(r * 32) * (KB_SPLIT * 2) + kbB),
          (__attribute__((address_space(3))) uint32_t*)((uint8_t*)Btile + r * 4096 + w * 1024), 16, 0, 0);
    }
    __syncthreads();
#pragma unroll
    for (int kk = 0; kk < 2; ++kk) {
      frag_ab af[4], bf[4];
#pragma unroll
      for (int i = 0; i < 4; ++i) {
        af[i] = *(const frag_ab*)((const uint8_t*)Atile + (wm + i * 16 + c16) * 128 + kk * 64 + q * 16);
        bf[i] = *(const frag_ab*)((const uint8_t*)Btile + (wn + i * 16 + c16) * 128 + kk * 64 + q * 16);
      }
#pragma unroll
      for (int i = 0; i < 4; ++i)
#pragma unroll
        for (int j = 0; j < 4; ++j)
          acc[i][j] = __builtin_amdgcn_mfma_f32_16x16x32_bf16(af[i], bf[j], acc[i][j], 0, 0, 0);
    }
    __syncthreads();
  }
  // C/D layout: col = lane&15, row = (lane>>4)*4 + reg
#pragma unroll
  for (int j = 0; j < 4; ++j) {
    int col = n0 + wn + j * 16 + c16;
    float bv = bias ? bias[col] : 0.f;
#pragma unroll
    for (int i = 0; i < 4; ++i) {
      int row = m0 + wm + i * 16 + q * 4;
#pragma unroll
      for (int r = 0; r < 4; ++r)
        C[(size_t)(row + r) * ldc + col] = acc[i][j][r] + bv;
    }
  }
}

// ---------------- rank-1 bias helpers: u = Qw@Kb, w = Kw@Qb, c = Qb.Kb ----------------
__global__ __launch_bounds__(64) void bias_prep(const float* __restrict__ Qw, const float* __restrict__ Kw,
                                                const float* __restrict__ Qb, const float* __restrict__ Kb,
                                                float* __restrict__ u, float* __restrict__ w,
                                                float* __restrict__ cbuf) {
  int k = blockIdx.x;
  int lane = threadIdx.x;
  if (k == NHID) {
    float s = 0.f;
    for (int j = lane; j < NHID; j += 64) s = fmaf(Qb[j], Kb[j], s);
#pragma unroll
    for (int o = 32; o > 0; o >>= 1) s += __shfl_down(s, o, 64);
    if (lane == 0) cbuf[0] = s;
    return;
  }
  float su = 0.f, sw = 0.f;
  for (int j = lane; j < NHID; j += 64) {
    su = fmaf(Qw[(size_t)k * NHID + j], Kb[j], su);
    sw = fmaf(Kw[(size_t)k * NHID + j], Qb[j], sw);
  }
#pragma unroll
  for (int o = 32; o > 0; o >>= 1) { su += __shfl_down(su, o, 64); sw += __shfl_down(sw, o, 64); }
  if (lane == 0) { u[k] = su; w[k] = sw; }
}

// ---------------- sliced SpMM: h[row] (+)= sum_{j in nbr, j in slice} xW[j] ----------------
// slice = 1024 rows = 2 MB of xW -> L2-resident during the launch.
__global__ __launch_bounds__(128) void spmm_slice(const float* __restrict__ xW,
                                                  const int* __restrict__ colidx,
                                                  const int* __restrict__ deg,
                                                  float* __restrict__ h, int s0, int init) {
  int row = blockIdx.x;
  int d = deg[row];
  __shared__ int scols[RCAP];
  __shared__ int scnt;
  int t = threadIdx.x;
  if (t == 0) scnt = 0;
  __syncthreads();
  int klo = s0 << 10, khi = klo + 1024;
  for (int i = t; i < d; i += 128) {
    int c = colidx[(size_t)row * RCAP + i];
    if (c >= klo && c < khi) { int p = atomicAdd(&scnt, 1); scols[p] = c; }
  }
  __syncthreads();
  int n = scnt;
  float4 acc = init ? make_float4(0.f, 0.f, 0.f, 0.f) : ((float4*)(h + (size_t)row * NHID))[t];
  int e = 0;
  for (; e + 4 <= n; e += 4) {
    float4 v0 = ((const float4*)(xW + (size_t)scols[e + 0] * NHID))[t];
    float4 v1 = ((const float4*)(xW + (size_t)scols[e + 1] * NHID))[t];
    float4 v2 = ((const float4*)(xW + (size_t)scols[e + 2] * NHID))[t];
    float4 v3 = ((const float4*)(xW + (size_t)scols[e + 3] * NHID))[t];
    acc.x += (v0.x + v1.x) + (v2.x + v3.x);
    acc.y += (v0.y + v1.y) + (v2.y + v3.y);
    acc.z += (v0.z + v1.z) + (v2.z + v3.z);
    acc.w += (v0.w + v1.w) + (v2.w + v3.w);
  }
  for (; e < n; ++e) {
    float4 v = ((const float4*)(xW + (size_t)scols[e] * NHID))[t];
    acc.x += v.x; acc.y += v.y; acc.z += v.z; acc.w += v.w;
  }
  ((float4*)(h + (size_t)row * NHID))[t] = acc;
}

// ---------------- h finalize: relu(h+b1), bf16 hi/lo split, fused a_i=h.u b_i=h.w ----------------
__global__ __launch_bounds__(128) void h_finalize(float* __restrict__ h, const float* __restrict__ b1,
                                                  const float* __restrict__ u, const float* __restrict__ w,
                                                  ushort* __restrict__ Hs, float* __restrict__ a_vec,
                                                  float* __restrict__ b_vec) {
  __shared__ float ra[2], rb[2];
  int row = blockIdx.x, t = threadIdx.x;
  int wv = t >> 6, lane = t & 63;
  float4 v = ((float4*)(h + (size_t)row * NHID))[t];
  float4 bv = ((const float4*)b1)[t];
  float4 o = make_float4(fmaxf(v.x + bv.x, 0.f), fmaxf(v.y + bv.y, 0.f),
                         fmaxf(v.z + bv.z, 0.f), fmaxf(v.w + bv.w, 0.f));
  ((float4*)(h + (size_t)row * NHID))[t] = o;
  ushort4 hi, lo;
  hi.x = f2bf(o.x); hi.y = f2bf(o.y); hi.z = f2bf(o.z); hi.w = f2bf(o.w);
  lo.x = f2bf(o.x - bf2f(hi.x)); lo.y = f2bf(o.y - bf2f(hi.y));
  lo.z = f2bf(o.z - bf2f(hi.z)); lo.w = f2bf(o.w - bf2f(hi.w));
  ushort* hr = Hs + (size_t)row * KA_SPLIT;
  ((ushort4*)hr)[t] = hi;
  ((ushort4*)(hr + 512))[t] = lo;
  float4 uv = ((const float4*)u)[t], wv4 = ((const float4*)w)[t];
  float sa = fmaf(o.x, uv.x, fmaf(o.y, uv.y, fmaf(o.z, uv.z, o.w * uv.w)));
  float sb = fmaf(o.x, wv4.x, fmaf(o.y, wv4.y, fmaf(o.z, wv4.z, o.w * wv4.w)));
#pragma unroll
  for (int off = 32; off > 0; off >>= 1) { sa += __shfl_down(sa, off, 64); sb += __shfl_down(sb, off, 64); }
  if (lane == 0) { ra[wv] = sa; rb[wv] = sb; }
  __syncthreads();
  if (t == 0) { a_vec[row] = ra[0] + ra[1]; b_vec[row] = rb[0] + rb[1]; }
}

// ---------------- sliced edge scores: score[e] = G_i . h_j for j in slice ----------------
__global__ __launch_bounds__(256) void score_slice(const float* __restrict__ G, int ldg,
                                                   const float* __restrict__ h,
                                                   const int* __restrict__ colidx,
                                                   const int* __restrict__ deg, int s0,
                                                   float* __restrict__ score) {
  __shared__ float gs[4][NHID];
  __shared__ int sel_e[4][RCAP];
  __shared__ int sel_c[4][RCAP];
  __shared__ int cnt[4];
  int t = threadIdx.x, wv = t >> 6, lane = t & 63;
  int row = blockIdx.x * 4 + wv;
  int d = deg[row];
  if (lane == 0) cnt[wv] = 0;
  __syncthreads();
  int klo = s0 << 10, khi = klo + 1024;
  for (int i = lane; i < d; i += 64) {
    int c = colidx[(size_t)row * RCAP + i];
    if (c >= klo && c < khi) { int p = atomicAdd(&cnt[wv], 1); sel_e[wv][p] = i; sel_c[wv][p] = c; }
  }
  const float4* gr = (const float4*)(G + (size_t)row * ldg);
  ((float4*)gs[wv])[lane] = gr[lane];
  ((float4*)gs[wv])[64 + lane] = gr[64 + lane];
  __syncthreads();
  int n = cnt[wv];
  int q = lane >> 4, u = lane & 15;
  const float4* gq = (const float4*)gs[wv] + u;
  for (int e0 = 0; e0 < n; e0 += 4) {
    int idx = e0 + q;
    bool act = idx < n;
    int col = sel_c[wv][act ? idx : 0];
    const float4* hr = (const float4*)(h + (size_t)col * NHID) + u;
    float s_a = 0.f, s_b = 0.f;
#pragma unroll
    for (int it = 0; it < 8; it += 2) {
      float4 h0 = hr[it * 16], g0 = gq[it * 16];
      float4 h1 = hr[(it + 1) * 16], g1 = gq[(it + 1) * 16];
      s_a = fmaf(h0.x, g0.x, s_a); s_a = fmaf(h0.y, g0.y, s_a);
      s_a = fmaf(h0.z, g0.z, s_a); s_a = fmaf(h0.w, g0.w, s_a);
      s_b = fmaf(h1.x, g1.x, s_b); s_b = fmaf(h1.y, g1.y, s_b);
      s_b = fmaf(h1.z, g1.z, s_b); s_b = fmaf(h1.w, g1.w, s_b);
    }
    float s = s_a + s_b;
    s += __shfl_down(s, 8, 16);
    s += __shfl_down(s, 4, 16);
    s += __shfl_down(s, 2, 16);
    s += __shfl_down(s, 1, 16);
    if (u == 0 && act) score[(size_t)row * RCAP + sel_e[wv][idx]] = s;
  }
}

// ---------------- T = colsum(Vh) ----------------
__global__ void zero_vec(float* __restrict__ T) { T[threadIdx.x] = 0.f; }

__global__ __launch_bounds__(256) void colsum_atomic(const float* __restrict__ Vh, int ldv,
                                                     float* __restrict__ T) {
  int t = threadIdx.x;
  int r0 = blockIdx.x * 128;
  float2 s = make_float2(0.f, 0.f);
  for (int r = 0; r < 128; ++r) {
    float2 v = ((const float2*)(Vh + (size_t)(r0 + r) * ldv))[t];
    s.x += v.x;
    s.y += v.y;
  }
  atomicAdd(&T[2 * t], s.x);
  atomicAdd(&T[2 * t + 1], s.y);
}

// ---------------- softmax (closed-form background) + thresholded aggregate + LayerNorm ----------------
__global__ __launch_bounds__(256) void softmax_agg_ln(const float* __restrict__ score,
                                                      const int* __restrict__ colidx, const int* __restrict__ deg,
                                                      const float* __restrict__ a_vec, const float* __restrict__ b_vec,
                                                      const float* __restrict__ cbuf,
                                                      const float* __restrict__ Vh, int ldv,
                                                      const float* __restrict__ T,
                                                      const float* __restrict__ lng, const float* __restrict__ lnb,
                                                      float* __restrict__ Xt) {
  __shared__ int scols[4][RCAP];
  __shared__ float sv[4][RCAP];
  int t = threadIdx.x, wv = t >> 6, lane = t & 63;
  int row = blockIdx.x * 4 + wv;
  int d = deg[row];
  float ai = a_vec[row] + cbuf[0];
  for (int i = lane; i < d; i += 64) {
    int c = colidx[(size_t)row * RCAP + i];
    scols[wv][i] = c;
    sv[wv][i] = score[(size_t)row * RCAP + i] + ai + b_vec[c];
  }
  __syncthreads();
  float m = 0.f;  // background score 0 participates in the max
  for (int i = lane; i < d; i += 64) m = fmaxf(m, sv[wv][i]);
#pragma unroll
  for (int o = 32; o > 0; o >>= 1) m = fmaxf(m, __shfl_xor(m, o, 64));
  float ssum = 0.f;
  for (int i = lane; i < d; i += 64) {
    float ex = expf(sv[wv][i] - m);
    sv[wv][i] = ex;
    ssum += ex;
  }
#pragma unroll
  for (int o = 32; o > 0; o >>= 1) ssum += __shfl_xor(ssum, o, 64);
  float em = expf(-m);
  float inv = 1.f / (ssum + (float)(N_NODES - d) * em);
  float ci = em * inv;
  __syncthreads();
  float4 a0 = make_float4(0.f, 0.f, 0.f, 0.f), a1 = a0;
  for (int e = 0; e < d; ++e) {
    float we = sv[wv][e] * inv;
    if (we > 1e-12f) {  // near-one-hot softmax: only ~1-3 edges survive
      const float4* vr = (const float4*)(Vh + (size_t)scols[wv][e] * ldv);
      float4 v0 = vr[lane * 2], v1 = vr[lane * 2 + 1];
      a0.x = fmaf(we, v0.x, a0.x); a0.y = fmaf(we, v0.y, a0.y);
      a0.z = fmaf(we, v0.z, a0.z); a0.w = fmaf(we, v0.w, a0.w);
      a1.x = fmaf(we, v1.x, a1.x); a1.y = fmaf(we, v1.y, a1.y);
      a1.z = fmaf(we, v1.z, a1.z); a1.w = fmaf(we, v1.w, a1.w);
    }
  }
  float4 t0 = ((const float4*)T)[lane * 2], t1 = ((const float4*)T)[lane * 2 + 1];
  a0.x = fmaf(ci, t0.x, a0.x); a0.y = fmaf(ci, t0.y, a0.y);
  a0.z = fmaf(ci, t0.z, a0.z); a0.w = fmaf(ci, t0.w, a0.w);
  a1.x = fmaf(ci, t1.x, a1.x); a1.y = fmaf(ci, t1.y, a1.y);
  a1.z = fmaf(ci, t1.z, a1.z); a1.w = fmaf(ci, t1.w, a1.w);
  float s1 = ((a0.x + a0.y) + (a0.z + a0.w)) + ((a1.x + a1.y) + (a1.z + a1.w));
  float s2 = ((a0.x * a0.x + a0.y * a0.y) + (a0.z * a0.z + a0.w * a0.w)) +
             ((a1.x * a1.x + a1.y * a1.y) + (a1.z * a1.z + a1.w * a1.w));
#pragma unroll
  for (int o = 32; o > 0; o >>= 1) { s1 += __shfl_xor(s1, o, 64); s2 += __shfl_xor(s2, o, 64); }
  float mu = s1 * (1.f / NHID);
  float var = s2 * (1.f / NHID) - mu * mu;
  float rstd = rsqrtf(var + 1e-5f);
  float4 g0 = ((const float4*)lng)[lane * 2], g1 = ((const float4*)lng)[lane * 2 + 1];
  float4 b0 = ((const float4*)lnb)[lane * 2], b1 = ((const float4*)lnb)[lane * 2 + 1];
  float4 o0, o1;
  o0.x = (a0.x - mu) * rstd * g0.x + b0.x;
  o0.y = (a0.y - mu) * rstd * g0.y + b0.y;
  o0.z = (a0.z - mu) * rstd * g0.z + b0.z;
  o0.w = (a0.w - mu) * rstd * g0.w + b0.w;
  o1.x = (a1.x - mu) * rstd * g1.x + b1.x;
  o1.y = (a1.y - mu) * rstd * g1.y + b1.y;
  o1.z = (a1.z - mu) * rstd * g1.z + b1.z;
  o1.w = (a1.w - mu) * rstd * g1.w + b1.w;
  float4* xr = (float4*)(Xt + (size_t)row * NHID);
  xr[lane * 2] = o0;
  xr[lane * 2 + 1] = o1;
}

// ---------------- Y = Xt @ W2 (512 -> 8), one wave per row ----------------
__global__ __launch_bounds__(256) void xt_w2(const float* __restrict__ Xt, const float* __restrict__ W2,
                                             float* __restrict__ Y) {
  __shared__ float w2s[NHID * NCLASS];
  int t = threadIdx.x;
  for (int i = t; i < NHID * NCLASS; i += 256) w2s[i] = W2[i];
  __syncthreads();
  int wv = t >> 6, lane = t & 63;
  int row = blockIdx.x * 4 + wv;
  const float4* xr = (const float4*)(Xt + (size_t)row * NHID);
  float4 x0 = xr[lane * 2], x1 = xr[lane * 2 + 1];
  float xv[8] = {x0.x, x0.y, x0.z, x0.w, x1.x, x1.y, x1.z, x1.w};
  float acc[NCLASS];
#pragma unroll
  for (int c = 0; c < NCLASS; ++c) acc[c] = 0.f;
#pragma unroll
  for (int kk = 0; kk < 8; ++kk) {
    int k = lane * 8 + kk;
#pragma unroll
    for (int c = 0; c < NCLASS; ++c) acc[c] = fmaf(xv[kk], w2s[k * NCLASS + c], acc[c]);
  }
#pragma unroll
  for (int c = 0; c < NCLASS; ++c)
#pragma unroll
    for (int o = 32; o > 0; o >>= 1) acc[c] += __shfl_down(acc[c], o, 64);
  if (lane == 0) {
    *(float4*)(Y + (size_t)row * NCLASS) = make_float4(acc[0], acc[1], acc[2], acc[3]);
    *(float4*)(Y + (size_t)row * NCLASS + 4) = make_float4(acc[4], acc[5], acc[6], acc[7]);
  }
}

// ---------------- z = adj @ Y + b2, softmax over 8 classes ----------------
__global__ __launch_bounds__(256) void final_spmm_softmax(const float* __restrict__ Y,
                                                          const int* __restrict__ colidx,
                                                          const int* __restrict__ deg,
                                                          const float* __restrict__ b2,
                                                          float* __restrict__ out) {
  int t = threadIdx.x;
  int wv = t >> 6, lane = t & 63;
  int row = blockIdx.x * 4 + wv;
  int d = deg[row];
  const int* cols = colidx + (size_t)row * RCAP;
  float acc[8];
#pragma unroll
  for (int c = 0; c < 8; ++c) acc[c] = 0.f;
  for (int e = lane; e < d; e += 64) {
    int col = cols[e];
    const float4* yr = (const float4*)(Y + (size_t)col * 8);
    float4 y0 = yr[0], y1 = yr[1];
    acc[0] += y0.x; acc[1] += y0.y; acc[2] += y0.z; acc[3] += y0.w;
    acc[4] += y1.x; acc[5] += y1.y; acc[6] += y1.z; acc[7] += y1.w;
  }
#pragma unroll
  for (int c = 0; c < 8; ++c)
#pragma unroll
    for (int o = 32; o > 0; o >>= 1) acc[c] += __shfl_down(acc[c], o, 64);
  if (lane == 0) {
    float z[8];
    float m = -1e30f;
#pragma unroll
    for (int c = 0; c < 8; ++c) { z[c] = acc[c] + b2[c]; m = fmaxf(m, z[c]); }
    float s = 0.f;
#pragma unroll
    for (int c = 0; c < 8; ++c) { z[c] = expf(z[c] - m); s += z[c]; }
    float inv = 1.f / s;
    *(float4*)(out + (size_t)row * 8) = make_float4(z[0] * inv, z[1] * inv, z[2] * inv, z[3] * inv);
    *(float4*)(out + (size_t)row * 8 + 4) = make_float4(z[4] * inv, z[5] * inv, z[6] * inv, z[7] * inv);
  }
}

extern "C" void kernel_launch(void* const* d_in, const int* in_sizes, int n_in,
                              void* d_out, int out_size, void* d_ws, size_t ws_size,
                              hipStream_t stream) {
  const float* adj = (const float*)d_in[0];
  const float* x = (const float*)d_in[1];
  const float* W1 = (const float*)d_in[2];
  const float* b1 = (const float*)d_in[3];
  const float* Qw = (const float*)d_in[4];
  const float* Qb = (const float*)d_in[5];
  const float* Kw = (const float*)d_in[6];
  const float* Kb = (const float*)d_in[7];
  const float* Vw = (const float*)d_in[8];
  const float* Vb = (const float*)d_in[9];
  const float* ln_g = (const float*)d_in[10];
  const float* ln_b = (const float*)d_in[11];
  const float* W2 = (const float*)d_in[12];
  const float* b2 = (const float*)d_in[13];
  float* out = (float*)d_out;

  char* ws = (char*)d_ws;
  size_t off = 0;
  auto alloc = [&](size_t bytes) -> void* {
    void* p = ws + off;
    off = (off + bytes + 255) & ~(size_t)255;
    return p;
  };
  int* colidx = (int*)alloc((size_t)N_NODES * RCAP * 4);
  int* deg = (int*)alloc((size_t)N_NODES * 4);
  float* bufA = (float*)alloc((size_t)N_NODES * NHID * 4);     // xW, then Xt
  float* bufB = (float*)alloc((size_t)N_NODES * NHID * 4);     // h
  float* GVh = (float*)alloc((size_t)N_NODES * 1024 * 4);      // [G | Vh], stride 1024
  ushort* Xs = (ushort*)alloc((size_t)N_NODES * KA_SPLIT * 2); // split x [hi|lo]
  ushort* Hs = (ushort*)alloc((size_t)N_NODES * KA_SPLIT * 2); // split h [hi|lo]
  ushort* W1ts = (ushort*)alloc((size_t)512 * KB_SPLIT * 2);   // split W1^T [hi|lo|hi]
  ushort* Bcts = (ushort*)alloc((size_t)1024 * KB_SPLIT * 2);  // split [M|Vw]^T
  float* KwT = (float*)alloc((size_t)512 * 512 * 4);
  float* Mmat = (float*)alloc((size_t)512 * 512 * 4);
  float* bcat = (float*)alloc((size_t)1024 * 4);
  float* edge_s = (float*)alloc((size_t)N_NODES * RCAP * 4);   // edge scores
  float* a_vec = (float*)alloc((size_t)N_NODES * 4);
  float* b_vec = (float*)alloc((size_t)N_NODES * 4);
  float* u_vec = (float*)alloc((size_t)NHID * 4);
  float* w_vec = (float*)alloc((size_t)NHID * 4);
  float* cbuf = (float*)alloc(256);
  float* T = (float*)alloc((size_t)NHID * 4);
  float* Y = (float*)alloc((size_t)N_NODES * NCLASS * 4);
  (void)in_sizes; (void)n_in; (void)out_size; (void)ws_size;

  // 1) sparse structure from dense adj
  build_ell<<<N_NODES, 256, 0, stream>>>(adj, colidx, deg);
  // 2) M = Qw@Kw^T (fp32, small); rank-1 bias terms
  transpose512<<<dim3(16, 16), dim3(32, 8), 0, stream>>>(Kw, KwT);
  bias_prep<<<NHID + 1, 64, 0, stream>>>(Qw, Kw, Qb, Kb, u_vec, w_vec, cbuf);
  sgemm64x128<<<dim3(4, 8), 256, 0, stream>>>(Qw, KwT, Mmat, 512, 512, 512, 512);
  // 3) splits; xW = x@W1 via bf16x3 MFMA
  split_a2<<<(N_NODES * 128) / 256, 256, 0, stream>>>(x, Xs);
  split_bt<<<(512 * 384) / 256, 256, 0, stream>>>(W1, W1ts, 512);
  mfma_gemm_bt<<<dim3(4, 64), 256, 0, stream>>>(Xs, W1ts, nullptr, bufA, 512);
  // 4) h = relu(adj@xW + b1): L2-sliced gather, then finalize (+split +a/b vectors)
  for (int s = 0; s < NSLICE; ++s)
    spmm_slice<<<N_NODES, 128, 0, stream>>>(bufA, colidx, deg, bufB, s, s == 0);
  h_finalize<<<N_NODES, 128, 0, stream>>>(bufB, b1, u_vec, w_vec, Hs, a_vec, b_vec);
  // 5) [G | Vh] = h @ [M | Vw] (+[0|Vb]) via MFMA
  split_bt_cat<<<(1024 * 384) / 256, 256, 0, stream>>>(Mmat, Vw, Bcts);
  build_bcat<<<4, 256, 0, stream>>>(Vb, bcat);
  mfma_gemm_bt<<<dim3(8, 64), 256, 0, stream>>>(Hs, Bcts, bcat, GVh, 1024);
  // 6) T = colsum(Vh)
  zero_vec<<<1, 512, 0, stream>>>(T);
  colsum_atomic<<<64, 256, 0, stream>>>(GVh + 512, 1024, T);
  // 7) edge scores, L2-sliced; then softmax + thresholded aggregate + LN -> Xt (bufA)
  for (int s = 0; s < NSLICE; ++s)
    score_slice<<<N_NODES / 4, 256, 0, stream>>>(GVh, 1024, bufB, colidx, deg, s, edge_s);
  softmax_agg_ln<<<N_NODES / 4, 256, 0, stream>>>(edge_s, colidx, deg, a_vec, b_vec, cbuf,
                                                  GVh + 512, 1024, T, ln_g, ln_b, bufA);
  // 8) Y = Xt @ W2 ; z = adj @ Y + b2 ; softmax
  xt_w2<<<N_NODES / 4, 256, 0, stream>>>(bufA, W2, Y);
  final_spmm_softmax<<<N_NODES / 4, 256, 0, stream>>>(Y, colidx, deg, b2, out);
}

// Round 5
// 803.312 us; speedup vs baseline: 1.3758x; 1.0112x over previous
//
#include <hip/hip_runtime.h>
#include <math.h>

#define N_NODES 8192
#define NFEAT 512
#define NHID 512
#define NCLASS 8
#define RCAP 192     // max row degree; Binomial(8192,0.01): mean 82, std 9 -> 192 is ~12 sigma
#define KB_SPLIT 1536  // B operand: [hi | lo | hi] bf16
#define KA_SPLIT 1024  // A operand: [hi | lo] bf16 (chunk map re-reads hi)
// per-(row,slice) degree ~ Binomial(1024,0.01): mean 10.2, std 3.2 -> cap 64 is ~17 sigma

// ---------- bf16 split helpers ----------
__device__ inline ushort f2bf(float f) {
  uint32_t u = __float_as_uint(f);
  uint32_t r = u + 0x7fffu + ((u >> 16) & 1u);
  return (ushort)(r >> 16);
}
__device__ inline float bf2f(ushort h) { return __uint_as_float(((uint32_t)h) << 16); }

// ---------------- adjacency: dense 0/1 -> ELL (single 256MB pass) ----------------
__global__ __launch_bounds__(256) void build_ell(const float* __restrict__ adj,
                                                 int* __restrict__ colidx,
                                                 int* __restrict__ deg) {
  int row = blockIdx.x;
  __shared__ int cnt;
  __shared__ int cols[RCAP];
  if (threadIdx.x == 0) cnt = 0;
  __syncthreads();
  const float4* arow = (const float4*)(adj + (size_t)row * N_NODES);
  for (int i = threadIdx.x; i < N_NODES / 4; i += 256) {
    float4 v = arow[i];
    int base = i * 4;
    if (v.x > 0.5f) { int p = atomicAdd(&cnt, 1); if (p < RCAP) cols[p] = base; }
    if (v.y > 0.5f) { int p = atomicAdd(&cnt, 1); if (p < RCAP) cols[p] = base + 1; }
    if (v.z > 0.5f) { int p = atomicAdd(&cnt, 1); if (p < RCAP) cols[p] = base + 2; }
    if (v.w > 0.5f) { int p = atomicAdd(&cnt, 1); if (p < RCAP) cols[p] = base + 3; }
  }
  __syncthreads();
  int d = cnt < RCAP ? cnt : RCAP;
  if (threadIdx.x == 0) deg[row] = d;
  for (int i = threadIdx.x; i < d; i += 256) colidx[(size_t)row * RCAP + i] = cols[i];
}

// ---------------- 512x512 transpose ----------------
__global__ void transpose512(const float* __restrict__ in, float* __restrict__ out) {
  __shared__ float tile[32][33];
  int x = blockIdx.x * 32 + threadIdx.x;
  int y0 = blockIdx.y * 32;
  for (int i = threadIdx.y; i < 32; i += 8)
    tile[i][threadIdx.x] = in[(size_t)(y0 + i) * 512 + x];
  __syncthreads();
  int xo = blockIdx.y * 32 + threadIdx.x;
  int yo0 = blockIdx.x * 32;
  for (int i = threadIdx.y; i < 32; i += 8)
    out[(size_t)(yo0 + i) * 512 + xo] = tile[threadIdx.x][i];
}

// ---------------- fp32 SGEMM (small 512^3: M = Qw@Kw^T) ----------------
__global__ __launch_bounds__(256) void sgemm64x128(const float* __restrict__ A,
                                                   const float* __restrict__ B,
                                                   float* __restrict__ C,
                                                   int M, int Nn, int K, int ldc) {
  __shared__ float As[16][68];
  __shared__ float Bs[16][132];
  const int tid = threadIdx.x;
  const int bm = blockIdx.y * 64, bn = blockIdx.x * 128;
  const int tx = tid & 15, ty = tid >> 4;
  const int arow = tid >> 2, acol = (tid & 3) << 2;
  const int brow = tid >> 4, bcol = (tid & 15) << 2;
  float acc[4][8];
#pragma unroll
  for (int i = 0; i < 4; ++i)
#pragma unroll
    for (int j = 0; j < 8; ++j) acc[i][j] = 0.f;
  const float* Ap = A + (size_t)(bm + arow) * K + acol;
  const float* Bp = B + (size_t)brow * Nn + bn + bcol;
  float4 av = *(const float4*)(Ap);
  float4 bv0 = *(const float4*)(Bp);
  float4 bv1 = *(const float4*)(Bp + 64);
  for (int k0 = 0; k0 < K; k0 += 16) {
    if (k0) __syncthreads();
    As[acol + 0][arow] = av.x;
    As[acol + 1][arow] = av.y;
    As[acol + 2][arow] = av.z;
    As[acol + 3][arow] = av.w;
    *(float4*)&Bs[brow][bcol] = bv0;
    *(float4*)&Bs[brow][bcol + 64] = bv1;
    __syncthreads();
    int kn = (k0 + 16 < K) ? k0 + 16 : 0;
    av = *(const float4*)(Ap + kn);
    bv0 = *(const float4*)(Bp + (size_t)kn * Nn);
    bv1 = *(const float4*)(Bp + (size_t)kn * Nn + 64);
#pragma unroll
    for (int kk = 0; kk < 16; ++kk) {
      float4 a = *(const float4*)&As[kk][ty << 2];
      float4 b0 = *(const float4*)&Bs[kk][tx << 2];
      float4 b1 = *(const float4*)&Bs[kk][(tx << 2) + 64];
      float ar[4] = {a.x, a.y, a.z, a.w};
      float br[8] = {b0.x, b0.y, b0.z, b0.w, b1.x, b1.y, b1.z, b1.w};
#pragma unroll
      for (int i = 0; i < 4; ++i)
#pragma unroll
        for (int j = 0; j < 8; ++j) acc[i][j] = fmaf(ar[i], br[j], acc[i][j]);
    }
  }
#pragma unroll
  for (int i = 0; i < 4; ++i) {
    int r = bm + (ty << 2) + i;
    *(float4*)(C + (size_t)r * ldc + bn + (tx << 2)) =
        make_float4(acc[i][0], acc[i][1], acc[i][2], acc[i][3]);
    *(float4*)(C + (size_t)r * ldc + bn + 64 + (tx << 2)) =
        make_float4(acc[i][4], acc[i][5], acc[i][6], acc[i][7]);
  }
}

// ---------------- split A [Mx512] fp32 -> [M x 1024] bf16 = [hi | lo] ----------------
__global__ __launch_bounds__(256) void split_a2(const float* __restrict__ A, ushort* __restrict__ As) {
  int idx = blockIdx.x * 256 + threadIdx.x;  // over M*128 float4s
  int m = idx >> 7, t = idx & 127;
  float4 v = ((const float4*)(A + (size_t)m * 512))[t];
  ushort4 hi, lo;
  hi.x = f2bf(v.x); hi.y = f2bf(v.y); hi.z = f2bf(v.z); hi.w = f2bf(v.w);
  lo.x = f2bf(v.x - bf2f(hi.x)); lo.y = f2bf(v.y - bf2f(hi.y));
  lo.z = f2bf(v.z - bf2f(hi.z)); lo.w = f2bf(v.w - bf2f(hi.w));
  ushort* row = As + (size_t)m * KA_SPLIT;
  ((ushort4*)row)[t] = hi;
  ((ushort4*)(row + 512))[t] = lo;
}

// ---------------- split+transpose B [512xNn] fp32 -> Bt [Nn x 1536] bf16 = [hi | lo | hi] ----------------
__global__ __launch_bounds__(256) void split_bt(const float* __restrict__ B, ushort* __restrict__ Bt, int Nn) {
  int idx = blockIdx.x * 256 + threadIdx.x;  // over Nn*384 ushort4s
  int n = idx / 384, t = idx % 384;
  int sec = t >> 7;  // 0:hi 1:lo 2:hi
  int k0 = (t & 127) << 2;
  ushort4 o;
  float f0 = B[(size_t)(k0 + 0) * Nn + n];
  float f1 = B[(size_t)(k0 + 1) * Nn + n];
  float f2 = B[(size_t)(k0 + 2) * Nn + n];
  float f3 = B[(size_t)(k0 + 3) * Nn + n];
  if (sec == 1) {
    o.x = f2bf(f0 - bf2f(f2bf(f0))); o.y = f2bf(f1 - bf2f(f2bf(f1)));
    o.z = f2bf(f2 - bf2f(f2bf(f2))); o.w = f2bf(f3 - bf2f(f2bf(f3)));
  } else {
    o.x = f2bf(f0); o.y = f2bf(f1); o.z = f2bf(f2); o.w = f2bf(f3);
  }
  ((ushort4*)(Bt + (size_t)n * KB_SPLIT))[t] = o;
}

// same, for Bcat = [Mmat | Vw] columns (Nn = 1024)
__global__ __launch_bounds__(256) void split_bt_cat(const float* __restrict__ Mm, const float* __restrict__ Vw,
                                                    ushort* __restrict__ Bt) {
  int idx = blockIdx.x * 256 + threadIdx.x;  // over 1024*384
  int n = idx / 384, t = idx % 384;
  const float* src = (n < 512) ? (Mm + n) : (Vw + (n - 512));
  int sec = t >> 7;
  int k0 = (t & 127) << 2;
  ushort4 o;
  float f0 = src[(size_t)(k0 + 0) * 512];
  float f1 = src[(size_t)(k0 + 1) * 512];
  float f2 = src[(size_t)(k0 + 2) * 512];
  float f3 = src[(size_t)(k0 + 3) * 512];
  if (sec == 1) {
    o.x = f2bf(f0 - bf2f(f2bf(f0))); o.y = f2bf(f1 - bf2f(f2bf(f1)));
    o.z = f2bf(f2 - bf2f(f2bf(f2))); o.w = f2bf(f3 - bf2f(f2bf(f3)));
  } else {
    o.x = f2bf(f0); o.y = f2bf(f1); o.z = f2bf(f2); o.w = f2bf(f3);
  }
  ((ushort4*)(Bt + (size_t)n * KB_SPLIT))[t] = o;
}

__global__ void build_bcat(const float* __restrict__ Vb, float* __restrict__ bcat) {
  int i = blockIdx.x * 256 + threadIdx.x;
  bcat[i] = (i < 512) ? 0.f : Vb[i - 512];
}

// ---------------- bf16x3 MFMA GEMM: C = A[hi|lo,K=1024] @ Bt[hi|lo|hi,K=1536]^T (+bias) ----------------
// chunk map: c in [0,24): A k-off = (c<8?c:c-8)*64  -> AhiBhi + AhiBlo + AloBhi
// optional fused column-sum (for T = colsum(Vh), cols >= 512)
using frag_ab = __attribute__((ext_vector_type(8))) short;
using frag_cd = __attribute__((ext_vector_type(4))) float;

__global__ __launch_bounds__(256) void mfma_gemm_bt(const ushort* __restrict__ A,
                                                    const ushort* __restrict__ Bt,
                                                    const float* __restrict__ bias,
                                                    float* __restrict__ C,
                                                    int ldc, float* __restrict__ Tsum) {
  __shared__ __align__(16) ushort Atile[128 * 64];
  __shared__ __align__(16) ushort Btile[128 * 64];
  const int tid = threadIdx.x;
  const int w = tid >> 6, lane = tid & 63;
  const int m0 = blockIdx.y * 128, n0 = blockIdx.x * 128;
  const int wm = (w >> 1) * 64, wn = (w & 1) * 64;
  const int q = lane >> 4, c16 = lane & 15;

  frag_cd acc[4][4];
#pragma unroll
  for (int i = 0; i < 4; ++i)
#pragma unroll
    for (int j = 0; j < 4; ++j) acc[i][j] = (frag_cd){0.f, 0.f, 0.f, 0.f};

  const int srow = (w << 3) + (lane >> 3);
  const int scolb = (lane & 7) << 4;
  const uint8_t* gA = (const uint8_t*)A + (size_t)(m0 + srow) * (KA_SPLIT * 2) + scolb;
  const uint8_t* gB = (const uint8_t*)Bt + (size_t)(n0 + srow) * (KB_SPLIT * 2) + scolb;

  for (int c = 0; c < 24; ++c) {
    const size_t kaB = (size_t)((c < 8 ? c : c - 8) * 128);
    const size_t kbB = (size_t)(c * 128);
#pragma unroll
    for (int r = 0; r < 4; ++r) {
      __builtin_amdgcn_global_load_lds(
          (const __attribute__((address_space(1))) uint32_t*)(gA + (size_t)(r * 32) * (KA_SPLIT * 2) + kaB),
          (__attribute__((address_space(3))) uint32_t*)((uint8_t*)Atile + r * 4096 + w * 1024), 16, 0, 0);
      __builtin_amdgcn_global_load_lds(
          (const __attribute__((address_space(1))) uint32_t*)(gB + (size_t)(r * 32) * (KB_SPLIT * 2) + kbB),
          (__attribute__((address_space(3))) uint32_t*)((uint8_t*)Btile + r * 4096 + w * 1024), 16, 0, 0);
    }
    __syncthreads();
#pragma unroll
    for (int kk = 0; kk < 2; ++kk) {
      frag_ab af[4], bf[4];
#pragma unroll
      for (int i = 0; i < 4; ++i) {
        af[i] = *(const frag_ab*)((const uint8_t*)Atile + (wm + i * 16 + c16) * 128 + kk * 64 + q * 16);
        bf[i] = *(const frag_ab*)((const uint8_t*)Btile + (wn + i * 16 + c16) * 128 + kk * 64 + q * 16);
      }
#pragma unroll
      for (int i = 0; i < 4; ++i)
#pragma unroll
        for (int j = 0; j < 4; ++j)
          acc[i][j] = __builtin_amdgcn_mfma_f32_16x16x32_bf16(af[i], bf[j], acc[i][j], 0, 0, 0);
    }
    __syncthreads();
  }
  // C/D layout: col = lane&15, row = (lane>>4)*4 + reg
#pragma unroll
  for (int j = 0; j < 4; ++j) {
    int col = n0 + wn + j * 16 + c16;
    float bv = bias ? bias[col] : 0.f;
    float csum = 0.f;
#pragma unroll
    for (int i = 0; i < 4; ++i) {
      int row = m0 + wm + i * 16 + q * 4;
#pragma unroll
      for (int r = 0; r < 4; ++r) {
        float v = acc[i][j][r] + bv;
        C[(size_t)(row + r) * ldc + col] = v;
        csum += v;
      }
    }
    if (Tsum && col >= 512) {  // fused T = colsum(Vh)
      csum += __shfl_xor(csum, 16, 64);
      csum += __shfl_xor(csum, 32, 64);
      if (q == 0) atomicAdd(&Tsum[col - 512], csum);
    }
  }
}

// ---------------- rank-1 bias helpers: u = Qw@Kb, w = Kw@Qb, c = Qb.Kb ----------------
__global__ __launch_bounds__(64) void bias_prep(const float* __restrict__ Qw, const float* __restrict__ Kw,
                                                const float* __restrict__ Qb, const float* __restrict__ Kb,
                                                float* __restrict__ u, float* __restrict__ w,
                                                float* __restrict__ cbuf) {
  int k = blockIdx.x;
  int lane = threadIdx.x;
  if (k == NHID) {
    float s = 0.f;
    for (int j = lane; j < NHID; j += 64) s = fmaf(Qb[j], Kb[j], s);
#pragma unroll
    for (int o = 32; o > 0; o >>= 1) s += __shfl_down(s, o, 64);
    if (lane == 0) cbuf[0] = s;
    return;
  }
  float su = 0.f, sw = 0.f;
  for (int j = lane; j < NHID; j += 64) {
    su = fmaf(Qw[(size_t)k * NHID + j], Kb[j], su);
    sw = fmaf(Kw[(size_t)k * NHID + j], Qb[j], sw);
  }
#pragma unroll
  for (int o = 32; o > 0; o >>= 1) { su += __shfl_down(su, o, 64); sw += __shfl_down(sw, o, 64); }
  if (lane == 0) { u[k] = su; w[k] = sw; }
}

// ---------------- fused SpMM: h = relu(adj@xW + b1), internal XCD-ordered slice loop ----------------
// One block per row; h accumulates in registers; edges bucketed by 1024-col slice in LDS.
// Blocks on the same XCD walk slices in the same rotation -> each XCD L2 holds ~2 MB of xW.
// Fused: bf16 hi/lo split of h, a_i = h.u, b_i = h.w.
__global__ __launch_bounds__(128) void spmm_fused(const float* __restrict__ xW,
                                                  const int* __restrict__ colidx,
                                                  const int* __restrict__ deg,
                                                  const float* __restrict__ b1,
                                                  const float* __restrict__ u, const float* __restrict__ w,
                                                  float* __restrict__ h, ushort* __restrict__ Hs,
                                                  float* __restrict__ a_vec, float* __restrict__ b_vec) {
  __shared__ int bls[512];   // 8 slices x 64 cap
  __shared__ int bcnt[8];
  __shared__ float ra[2], rb[2];
  int row = blockIdx.x, t = threadIdx.x;
  int d = deg[row];
  if (t < 8) bcnt[t] = 0;
  __syncthreads();
  for (int i = t; i < d; i += 128) {
    int c = colidx[(size_t)row * RCAP + i];
    int s = c >> 10;
    int p = atomicAdd(&bcnt[s], 1);
    bls[(s << 6) | p] = c;
  }
  __syncthreads();
  float4 acc = make_float4(0.f, 0.f, 0.f, 0.f);
  int xcd = blockIdx.x & 7;
  for (int k = 0; k < 8; ++k) {
    int s = (xcd + k) & 7;
    int n = bcnt[s];
    const int* bp = &bls[s << 6];
    int e = 0;
    for (; e + 4 <= n; e += 4) {
      float4 v0 = ((const float4*)(xW + (size_t)bp[e + 0] * NHID))[t];
      float4 v1 = ((const float4*)(xW + (size_t)bp[e + 1] * NHID))[t];
      float4 v2 = ((const float4*)(xW + (size_t)bp[e + 2] * NHID))[t];
      float4 v3 = ((const float4*)(xW + (size_t)bp[e + 3] * NHID))[t];
      acc.x += (v0.x + v1.x) + (v2.x + v3.x);
      acc.y += (v0.y + v1.y) + (v2.y + v3.y);
      acc.z += (v0.z + v1.z) + (v2.z + v3.z);
      acc.w += (v0.w + v1.w) + (v2.w + v3.w);
    }
    for (; e < n; ++e) {
      float4 v = ((const float4*)(xW + (size_t)bp[e] * NHID))[t];
      acc.x += v.x; acc.y += v.y; acc.z += v.z; acc.w += v.w;
    }
  }
  // finalize: +b1, relu, write h, split, a/b dots
  float4 bv = ((const float4*)b1)[t];
  float4 o = make_float4(fmaxf(acc.x + bv.x, 0.f), fmaxf(acc.y + bv.y, 0.f),
                         fmaxf(acc.z + bv.z, 0.f), fmaxf(acc.w + bv.w, 0.f));
  ((float4*)(h + (size_t)row * NHID))[t] = o;
  ushort4 hi, lo;
  hi.x = f2bf(o.x); hi.y = f2bf(o.y); hi.z = f2bf(o.z); hi.w = f2bf(o.w);
  lo.x = f2bf(o.x - bf2f(hi.x)); lo.y = f2bf(o.y - bf2f(hi.y));
  lo.z = f2bf(o.z - bf2f(hi.z)); lo.w = f2bf(o.w - bf2f(hi.w));
  ushort* hr = Hs + (size_t)row * KA_SPLIT;
  ((ushort4*)hr)[t] = hi;
  ((ushort4*)(hr + 512))[t] = lo;
  float4 uv = ((const float4*)u)[t], wv4 = ((const float4*)w)[t];
  float sa = fmaf(o.x, uv.x, fmaf(o.y, uv.y, fmaf(o.z, uv.z, o.w * uv.w)));
  float sb = fmaf(o.x, wv4.x, fmaf(o.y, wv4.y, fmaf(o.z, wv4.z, o.w * wv4.w)));
  int wv = t >> 6, lane = t & 63;
#pragma unroll
  for (int off = 32; off > 0; off >>= 1) { sa += __shfl_down(sa, off, 64); sb += __shfl_down(sb, off, 64); }
  if (lane == 0) { ra[wv] = sa; rb[wv] = sb; }
  __syncthreads();
  if (t == 0) { a_vec[row] = ra[0] + ra[1]; b_vec[row] = rb[0] + rb[1]; }
}

// ---------------- zero T ----------------
__global__ void zero_vec(float* __restrict__ T) { T[threadIdx.x] = 0.f; }

// ---------------- fused: edge scores (XCD-ordered slices) -> softmax -> aggregate -> LayerNorm ----------------
// One wave per row (4/block). Quarter-wave per edge. s_ij = G_i.h_j + a_i + b_j + c;
// background (masked zeros) handled in closed form; near-one-hot softmax -> thresholded gather.
__global__ __launch_bounds__(256) void score_softmax_agg_ln(
    const float* __restrict__ G, int ldg, const float* __restrict__ h,
    const int* __restrict__ colidx, const int* __restrict__ deg,
    const float* __restrict__ a_vec, const float* __restrict__ b_vec,
    const float* __restrict__ cbuf, const float* __restrict__ Vh, int ldv,
    const float* __restrict__ T, const float* __restrict__ lng,
    const float* __restrict__ lnb, float* __restrict__ Xt) {
  __shared__ float gs[4][NHID];
  __shared__ int bls[4][512];   // packed (col<<8)|edge_idx, 8 slices x 64 cap
  __shared__ int bcnt[4][8];
  __shared__ int scols[4][RCAP];
  __shared__ float sv[4][RCAP];
  int t = threadIdx.x, wv = t >> 6, lane = t & 63;
  int row = blockIdx.x * 4 + wv;
  int d = deg[row];
  if (lane < 8) bcnt[wv][lane] = 0;
  const float4* gr = (const float4*)(G + (size_t)row * ldg);
  ((float4*)gs[wv])[lane] = gr[lane];
  ((float4*)gs[wv])[64 + lane] = gr[64 + lane];
  __syncthreads();
  for (int i = lane; i < d; i += 64) {
    int c = colidx[(size_t)row * RCAP + i];
    scols[wv][i] = c;
    int s = c >> 10;
    int p = atomicAdd(&bcnt[wv][s], 1);
    bls[wv][(s << 6) | p] = (c << 8) | i;
  }
  __syncthreads();
  float ai = a_vec[row] + cbuf[0];
  int xcd = blockIdx.x & 7;
  int q = lane >> 4, u = lane & 15;
  const float4* gq = (const float4*)gs[wv] + u;
  for (int k = 0; k < 8; ++k) {
    int s = (xcd + k) & 7;
    int n = bcnt[wv][s];
    for (int e0 = 0; e0 < n; e0 += 4) {
      int idx = e0 + q;
      bool act = idx < n;
      int pack = bls[wv][(s << 6) | (act ? idx : 0)];
      int col = pack >> 8;
      const float4* hr = (const float4*)(h + (size_t)col * NHID) + u;
      float s_a = 0.f, s_b = 0.f;
#pragma unroll
      for (int it = 0; it < 8; it += 2) {
        float4 h0 = hr[it * 16], g0 = gq[it * 16];
        float4 h1 = hr[(it + 1) * 16], g1 = gq[(it + 1) * 16];
        s_a = fmaf(h0.x, g0.x, s_a); s_a = fmaf(h0.y, g0.y, s_a);
        s_a = fmaf(h0.z, g0.z, s_a); s_a = fmaf(h0.w, g0.w, s_a);
        s_b = fmaf(h1.x, g1.x, s_b); s_b = fmaf(h1.y, g1.y, s_b);
        s_b = fmaf(h1.z, g1.z, s_b); s_b = fmaf(h1.w, g1.w, s_b);
      }
      float sc = s_a + s_b;
      sc += __shfl_down(sc, 8, 16);
      sc += __shfl_down(sc, 4, 16);
      sc += __shfl_down(sc, 2, 16);
      sc += __shfl_down(sc, 1, 16);
      if (u == 0 && act) sv[wv][pack & 255] = sc + ai + b_vec[col];
    }
  }
  __syncthreads();
  float m = 0.f;  // background score 0 participates in the max
  for (int i = lane; i < d; i += 64) m = fmaxf(m, sv[wv][i]);
#pragma unroll
  for (int o = 32; o > 0; o >>= 1) m = fmaxf(m, __shfl_xor(m, o, 64));
  float ssum = 0.f;
  for (int i = lane; i < d; i += 64) {
    float ex = expf(sv[wv][i] - m);
    sv[wv][i] = ex;
    ssum += ex;
  }
#pragma unroll
  for (int o = 32; o > 0; o >>= 1) ssum += __shfl_xor(ssum, o, 64);
  float em = expf(-m);
  float inv = 1.f / (ssum + (float)(N_NODES - d) * em);
  float ci = em * inv;
  __syncthreads();
  float4 a0 = make_float4(0.f, 0.f, 0.f, 0.f), a1 = a0;
  for (int e = 0; e < d; ++e) {
    float we = sv[wv][e] * inv;
    if (we > 1e-12f) {  // near-one-hot softmax: only ~1-3 edges survive
      const float4* vr = (const float4*)(Vh + (size_t)scols[wv][e] * ldv);
      float4 v0 = vr[lane * 2], v1 = vr[lane * 2 + 1];
      a0.x = fmaf(we, v0.x, a0.x); a0.y = fmaf(we, v0.y, a0.y);
      a0.z = fmaf(we, v0.z, a0.z); a0.w = fmaf(we, v0.w, a0.w);
      a1.x = fmaf(we, v1.x, a1.x); a1.y = fmaf(we, v1.y, a1.y);
      a1.z = fmaf(we, v1.z, a1.z); a1.w = fmaf(we, v1.w, a1.w);
    }
  }
  float4 t0 = ((const float4*)T)[lane * 2], t1 = ((const float4*)T)[lane * 2 + 1];
  a0.x = fmaf(ci, t0.x, a0.x); a0.y = fmaf(ci, t0.y, a0.y);
  a0.z = fmaf(ci, t0.z, a0.z); a0.w = fmaf(ci, t0.w, a0.w);
  a1.x = fmaf(ci, t1.x, a1.x); a1.y = fmaf(ci, t1.y, a1.y);
  a1.z = fmaf(ci, t1.z, a1.z); a1.w = fmaf(ci, t1.w, a1.w);
  float s1 = ((a0.x + a0.y) + (a0.z + a0.w)) + ((a1.x + a1.y) + (a1.z + a1.w));
  float s2 = ((a0.x * a0.x + a0.y * a0.y) + (a0.z * a0.z + a0.w * a0.w)) +
             ((a1.x * a1.x + a1.y * a1.y) + (a1.z * a1.z + a1.w * a1.w));
#pragma unroll
  for (int o = 32; o > 0; o >>= 1) { s1 += __shfl_xor(s1, o, 64); s2 += __shfl_xor(s2, o, 64); }
  float mu = s1 * (1.f / NHID);
  float var = s2 * (1.f / NHID) - mu * mu;
  float rstd = rsqrtf(var + 1e-5f);
  float4 g0 = ((const float4*)lng)[lane * 2], g1 = ((const float4*)lng)[lane * 2 + 1];
  float4 b0 = ((const float4*)lnb)[lane * 2], b1 = ((const float4*)lnb)[lane * 2 + 1];
  float4 o0, o1;
  o0.x = (a0.x - mu) * rstd * g0.x + b0.x;
  o0.y = (a0.y - mu) * rstd * g0.y + b0.y;
  o0.z = (a0.z - mu) * rstd * g0.z + b0.z;
  o0.w = (a0.w - mu) * rstd * g0.w + b0.w;
  o1.x = (a1.x - mu) * rstd * g1.x + b1.x;
  o1.y = (a1.y - mu) * rstd * g1.y + b1.y;
  o1.z = (a1.z - mu) * rstd * g1.z + b1.z;
  o1.w = (a1.w - mu) * rstd * g1.w + b1.w;
  float4* xr = (float4*)(Xt + (size_t)row * NHID);
  xr[lane * 2] = o0;
  xr[lane * 2 + 1] = o1;
}

// ---------------- Y = Xt @ W2 (512 -> 8), one wave per row ----------------
__global__ __launch_bounds__(256) void xt_w2(const float* __restrict__ Xt, const float* __restrict__ W2,
                                             float* __restrict__ Y) {
  __shared__ float w2s[NHID * NCLASS];
  int t = threadIdx.x;
  for (int i = t; i < NHID * NCLASS; i += 256) w2s[i] = W2[i];
  __syncthreads();
  int wv = t >> 6, lane = t & 63;
  int row = blockIdx.x * 4 + wv;
  const float4* xr = (const float4*)(Xt + (size_t)row * NHID);
  float4 x0 = xr[lane * 2], x1 = xr[lane * 2 + 1];
  float xv[8] = {x0.x, x0.y, x0.z, x0.w, x1.x, x1.y, x1.z, x1.w};
  float acc[NCLASS];
#pragma unroll
  for (int c = 0; c < NCLASS; ++c) acc[c] = 0.f;
#pragma unroll
  for (int kk = 0; kk < 8; ++kk) {
    int k = lane * 8 + kk;
#pragma unroll
    for (int c = 0; c < NCLASS; ++c) acc[c] = fmaf(xv[kk], w2s[k * NCLASS + c], acc[c]);
  }
#pragma unroll
  for (int c = 0; c < NCLASS; ++c)
#pragma unroll
    for (int o = 32; o > 0; o >>= 1) acc[c] += __shfl_down(acc[c], o, 64);
  if (lane == 0) {
    *(float4*)(Y + (size_t)row * NCLASS) = make_float4(acc[0], acc[1], acc[2], acc[3]);
    *(float4*)(Y + (size_t)row * NCLASS + 4) = make_float4(acc[4], acc[5], acc[6], acc[7]);
  }
}

// ---------------- z = adj @ Y + b2, softmax over 8 classes ----------------
__global__ __launch_bounds__(256) void final_spmm_softmax(const float* __restrict__ Y,
                                                          const int* __restrict__ colidx,
                                                          const int* __restrict__ deg,
                                                          const float* __restrict__ b2,
                                                          float* __restrict__ out) {
  int t = threadIdx.x;
  int wv = t >> 6, lane = t & 63;
  int row = blockIdx.x * 4 + wv;
  int d = deg[row];
  const int* cols = colidx + (size_t)row * RCAP;
  float acc[8];
#pragma unroll
  for (int c = 0; c < 8; ++c) acc[c] = 0.f;
  for (int e = lane; e < d; e += 64) {
    int col = cols[e];
    const float4* yr = (const float4*)(Y + (size_t)col * 8);
    float4 y0 = yr[0], y1 = yr[1];
    acc[0] += y0.x; acc[1] += y0.y; acc[2] += y0.z; acc[3] += y0.w;
    acc[4] += y1.x; acc[5] += y1.y; acc[6] += y1.z; acc[7] += y1.w;
  }
#pragma unroll
  for (int c = 0; c < 8; ++c)
#pragma unroll
    for (int o = 32; o > 0; o >>= 1) acc[c] += __shfl_down(acc[c], o, 64);
  if (lane == 0) {
    float z[8];
    float m = -1e30f;
#pragma unroll
    for (int c = 0; c < 8; ++c) { z[c] = acc[c] + b2[c]; m = fmaxf(m, z[c]); }
    float s = 0.f;
#pragma unroll
    for (int c = 0; c < 8; ++c) { z[c] = expf(z[c] - m); s += z[c]; }
    float inv = 1.f / s;
    *(float4*)(out + (size_t)row * 8) = make_float4(z[0] * inv, z[1] * inv, z[2] * inv, z[3] * inv);
    *(float4*)(out + (size_t)row * 8 + 4) = make_float4(z[4] * inv, z[5] * inv, z[6] * inv, z[7] * inv);
  }
}

extern "C" void kernel_launch(void* const* d_in, const int* in_sizes, int n_in,
                              void* d_out, int out_size, void* d_ws, size_t ws_size,
                              hipStream_t stream) {
  const float* adj = (const float*)d_in[0];
  const float* x = (const float*)d_in[1];
  const float* W1 = (const float*)d_in[2];
  const float* b1 = (const float*)d_in[3];
  const float* Qw = (const float*)d_in[4];
  const float* Qb = (const float*)d_in[5];
  const float* Kw = (const float*)d_in[6];
  const float* Kb = (const float*)d_in[7];
  const float* Vw = (const float*)d_in[8];
  const float* Vb = (const float*)d_in[9];
  const float* ln_g = (const float*)d_in[10];
  const float* ln_b = (const float*)d_in[11];
  const float* W2 = (const float*)d_in[12];
  const float* b2 = (const float*)d_in[13];
  float* out = (float*)d_out;

  char* ws = (char*)d_ws;
  size_t off = 0;
  auto alloc = [&](size_t bytes) -> void* {
    void* p = ws + off;
    off = (off + bytes + 255) & ~(size_t)255;
    return p;
  };
  int* colidx = (int*)alloc((size_t)N_NODES * RCAP * 4);
  int* deg = (int*)alloc((size_t)N_NODES * 4);
  float* bufA = (float*)alloc((size_t)N_NODES * NHID * 4);     // xW, then Xt
  float* bufB = (float*)alloc((size_t)N_NODES * NHID * 4);     // h
  float* GVh = (float*)alloc((size_t)N_NODES * 1024 * 4);      // [G | Vh], stride 1024
  ushort* Xs = (ushort*)alloc((size_t)N_NODES * KA_SPLIT * 2); // split x [hi|lo]
  ushort* Hs = (ushort*)alloc((size_t)N_NODES * KA_SPLIT * 2); // split h [hi|lo]
  ushort* W1ts = (ushort*)alloc((size_t)512 * KB_SPLIT * 2);   // split W1^T [hi|lo|hi]
  ushort* Bcts = (ushort*)alloc((size_t)1024 * KB_SPLIT * 2);  // split [M|Vw]^T
  float* KwT = (float*)alloc((size_t)512 * 512 * 4);
  float* Mmat = (float*)alloc((size_t)512 * 512 * 4);
  float* bcat = (float*)alloc((size_t)1024 * 4);
  float* a_vec = (float*)alloc((size_t)N_NODES * 4);
  float* b_vec = (float*)alloc((size_t)N_NODES * 4);
  float* u_vec = (float*)alloc((size_t)NHID * 4);
  float* w_vec = (float*)alloc((size_t)NHID * 4);
  float* cbuf = (float*)alloc(256);
  float* T = (float*)alloc((size_t)NHID * 4);
  float* Y = (float*)alloc((size_t)N_NODES * NCLASS * 4);
  (void)in_sizes; (void)n_in; (void)out_size; (void)ws_size;

  // 1) sparse structure from dense adj
  build_ell<<<N_NODES, 256, 0, stream>>>(adj, colidx, deg);
  // 2) M = Qw@Kw^T (fp32, small); rank-1 bias terms
  transpose512<<<dim3(16, 16), dim3(32, 8), 0, stream>>>(Kw, KwT);
  bias_prep<<<NHID + 1, 64, 0, stream>>>(Qw, Kw, Qb, Kb, u_vec, w_vec, cbuf);
  sgemm64x128<<<dim3(4, 8), 256, 0, stream>>>(Qw, KwT, Mmat, 512, 512, 512, 512);
  // 3) splits; xW = x@W1 via bf16x3 MFMA
  split_a2<<<(N_NODES * 128) / 256, 256, 0, stream>>>(x, Xs);
  split_bt<<<(512 * 384) / 256, 256, 0, stream>>>(W1, W1ts, 512);
  mfma_gemm_bt<<<dim3(4, 64), 256, 0, stream>>>(Xs, W1ts, nullptr, bufA, 512, nullptr);
  // 4) h = relu(adj@xW + b1): single-launch fused sliced gather + split + a/b vectors
  spmm_fused<<<N_NODES, 128, 0, stream>>>(bufA, colidx, deg, b1, u_vec, w_vec, bufB, Hs, a_vec, b_vec);
  // 5) [G | Vh] = h @ [M | Vw] (+[0|Vb]) via MFMA, fused T = colsum(Vh)
  split_bt_cat<<<(1024 * 384) / 256, 256, 0, stream>>>(Mmat, Vw, Bcts);
  build_bcat<<<4, 256, 0, stream>>>(Vb, bcat);
  zero_vec<<<1, 512, 0, stream>>>(T);
  mfma_gemm_bt<<<dim3(8, 64), 256, 0, stream>>>(Hs, Bcts, bcat, GVh, 1024, T);
  // 6) fused scores (sliced) + softmax + thresholded aggregate + LN -> Xt (bufA)
  score_softmax_agg_ln<<<N_NODES / 4, 256, 0, stream>>>(GVh, 1024, bufB, colidx, deg, a_vec, b_vec,
                                                        cbuf, GVh + 512, 1024, T, ln_g, ln_b, bufA);
  // 7) Y = Xt @ W2 ; z = adj @ Y + b2 ; softmax
  xt_w2<<<N_NODES / 4, 256, 0, stream>>>(bufA, W2, Y);
  final_spmm_softmax<<<N_NODES / 4, 256, 0, stream>>>(Y, colidx, deg, b2, out);
}